// Round 17
// baseline (486.982 us; speedup 1.0000x reference)
//
#include <hip/hip_runtime.h>
#include <hip/hip_fp16.h>

typedef __attribute__((ext_vector_type(4))) float f32x4;
typedef __attribute__((ext_vector_type(8))) _Float16 f16x8;
typedef __attribute__((ext_vector_type(4))) _Float16 f16x4;

// ---------------- helpers ----------------
__device__ __forceinline__ void gload_lds16(const void* gp, void* lp) {
    __builtin_amdgcn_global_load_lds(
        (const __attribute__((address_space(1))) void*)gp,
        (__attribute__((address_space(3))) void*)lp, 16, 0, 0);
}

// Barrier as inline asm WITH memory clobber: raw __builtin_amdgcn_s_barrier() is
// IntrNoMem in LLVM, so LDS/global ops can be reordered across it (round-7 race).
__device__ __forceinline__ void barrier_fenced() {
    asm volatile("s_barrier" ::: "memory");
}

// ---------------- RoPE tables: cos/sin (2048 x 512) f32 ----------------
__global__ void rope_tables_k(float* __restrict__ cosT, float* __restrict__ sinT) {
    int idx = blockIdx.x * 256 + threadIdx.x;
    int s = idx >> 9, j = idx & 511;
    float invf = exp2f(-13.287712379549449f * (float)j * (1.0f / 512.0f)); // 10000^(-j/512)
    float ang = (float)s * invf;
    float sn, cs;
    sincosf(ang, &sn, &cs);
    cosT[idx] = cs;
    sinT[idx] = sn;
}

// ---------------- f32 -> f16 straight convert ----------------
__global__ void f32_to_f16_vec(const float* __restrict__ in, _Float16* __restrict__ out) {
    long i = ((long)blockIdx.x * 256 + threadIdx.x) * 4;
    f32x4 v = *(const f32x4*)(in + i);
    f16x4 h;
#pragma unroll
    for (int e = 0; e < 4; ++e) h[e] = (_Float16)v[e];
    *(f16x4*)(out + i) = h;
}

// ---------------- transpose + convert: in (R x C) f32 -> out (C x R) f16 ----------------
__global__ void transpose_f32_to_f16(const float* __restrict__ in, _Float16* __restrict__ out,
                                     int R, int C) {
    __shared__ _Float16 tile[32][36];
    const int c0 = blockIdx.x * 32, r0 = blockIdx.y * 32;
    const int t = threadIdx.x;
    const int r = t >> 3, c4 = (t & 7) * 4;
    f32x4 v = *(const f32x4*)(in + (long)(r0 + r) * C + c0 + c4);
    f16x4 h;
#pragma unroll
    for (int e = 0; e < 4; ++e) h[e] = (_Float16)v[e];
    *(f16x4*)&tile[r][c4] = h;
    __syncthreads();
    const int oc = t >> 3, o4 = (t & 7) * 4;
    f16x4 o;
#pragma unroll
    for (int e = 0; e < 4; ++e) o[e] = tile[o4 + e][oc];
    *(f16x4*)(out + (long)(c0 + oc) * R + r0 + o4) = o;
}

// ---------------- RoPE in-place on qkv rows (head-mixing: pair j with j+1024) ----------------
__global__ void rope_inplace(_Float16* __restrict__ qkv, const float* __restrict__ cosT,
                             const float* __restrict__ sinT) {
    const int row = blockIdx.x;            // b*2048 + s
    const int s = row & 2047;
    const int j0 = threadIdx.x * 4;        // [0,1024)
    _Float16* base = qkv + (long)row * 6144;
    f16x4 q0 = *(const f16x4*)(base + j0);
    f16x4 q1 = *(const f16x4*)(base + 1024 + j0);
    f16x4 k0 = *(const f16x4*)(base + 2048 + j0);
    f16x4 k1 = *(const f16x4*)(base + 3072 + j0);
    const int jj = j0 & 511;
    f32x4 cs = *(const f32x4*)(cosT + (long)s * 512 + jj);
    f32x4 sn = *(const f32x4*)(sinT + (long)s * 512 + jj);
    f16x4 oq0, oq1, ok0, ok1;
#pragma unroll
    for (int e = 0; e < 4; ++e) {
        float a = (float)q0[e], b = (float)q1[e];
        oq0[e] = (_Float16)(a * cs[e] - b * sn[e]);
        oq1[e] = (_Float16)(b * cs[e] + a * sn[e]);
        float c = (float)k0[e], d = (float)k1[e];
        ok0[e] = (_Float16)(c * cs[e] - d * sn[e]);
        ok1[e] = (_Float16)(d * cs[e] + c * sn[e]);
    }
    *(f16x4*)(base + j0) = oq0;
    *(f16x4*)(base + 1024 + j0) = oq1;
    *(f16x4*)(base + 2048 + j0) = ok0;
    *(f16x4*)(base + 3072 + j0) = ok1;
}

// ---------------- V transpose: qkv v-part (b,s,h,d) -> vT (b,h,d,s) f16 ----------------
__global__ void v_transpose(const _Float16* __restrict__ qkv, _Float16* __restrict__ vT) {
    __shared__ _Float16 tile[32][36];
    const int z = blockIdx.z, b = z >> 1, h = z & 1;
    const int s0 = blockIdx.x * 32, d0 = blockIdx.y * 32;
    const int t = threadIdx.x;
    const int r = t >> 3, c4 = (t & 7) * 4;
    const _Float16* src = qkv + (long)(b * 2048 + s0 + r) * 6144 + 4096 + h * 1024 + d0 + c4;
    *(f16x4*)&tile[r][c4] = *(const f16x4*)src;
    __syncthreads();
    const int dr = t >> 3, sc = (t & 7) * 4;
    f16x4 o;
#pragma unroll
    for (int e = 0; e < 4; ++e) o[e] = tile[sc + e][dr];
    *(f16x4*)(vT + ((long)z * 1024 + d0 + dr) * 2048 + s0 + sc) = o;
}

// ---------------- softmax on f32 rows (2048), writes f16 P in place (fallback path) ----------------
__global__ __launch_bounds__(256) void softmax_rows_f32(float* __restrict__ S, float scale) {
    const int wid = threadIdx.x >> 6, lane = threadIdx.x & 63;
    const long row = (long)blockIdx.x * 4 + wid;
    float* rp = S + row * 2048;
    f32x4 v[8];
    float mx = -1e30f;
#pragma unroll
    for (int i = 0; i < 8; ++i) {
        v[i] = *(const f32x4*)(rp + (i * 64 + lane) * 4);
#pragma unroll
        for (int e = 0; e < 4; ++e) mx = fmaxf(mx, v[i][e]);
    }
#pragma unroll
    for (int o = 32; o > 0; o >>= 1) mx = fmaxf(mx, __shfl_xor(mx, o, 64));
    float sum = 0.f;
#pragma unroll
    for (int i = 0; i < 8; ++i)
#pragma unroll
        for (int e = 0; e < 4; ++e) {
            float p = __expf(scale * (v[i][e] - mx));
            v[i][e] = p; sum += p;
        }
#pragma unroll
    for (int o = 32; o > 0; o >>= 1) sum += __shfl_xor(sum, o, 64);
    float inv = 1.0f / sum;
    _Float16* wp = (_Float16*)S + row * 4096;
#pragma unroll
    for (int i = 0; i < 8; ++i) {
        f16x4 h;
#pragma unroll
        for (int e = 0; e < 4; ++e) h[e] = (_Float16)(v[i][e] * inv);
        *(f16x4*)(wp + (i * 64 + lane) * 4) = h;
    }
}

// ---------------- row-sum of f16 rows (2048 wide) -> f32 sums ----------------
__global__ __launch_bounds__(256) void rowsum_f16(const _Float16* __restrict__ S,
                                                  float* __restrict__ l) {
    const int wid = threadIdx.x >> 6, lane = threadIdx.x & 63;
    const long row = (long)blockIdx.x * 4 + wid;
    const _Float16* rp = S + row * 2048;
    float sum = 0.f;
#pragma unroll
    for (int i = 0; i < 4; ++i) {
        f16x8 v = *(const f16x8*)(rp + i * 512 + lane * 8);
#pragma unroll
        for (int e = 0; e < 8; ++e) sum += (float)v[e];
    }
#pragma unroll
    for (int o = 32; o > 0; o >>= 1) sum += __shfl_xor(sum, o, 64);
    if (lane == 0) l[row] = sum;
}

// ---------------- GEMM 256x256, BK=64, 8 waves, A-ring3 + B-ring2, distance-2 prefetch ----------------
// Round-15's 2-barrier schedule with SYMMETRIC distance-2 staging: A(g+2) staged in half-A
// (slot (g+2)%3 last read tile g-1, closed by tile-g start barrier), B(g+2) staged in half-B
// (slot g&1; mid-tile barrier closes this tile's B reads first). Gate = vmcnt(8): retires
// A(g+1)+B(g+1) — both issued a FULL tile (~1200cy) earlier, covering HBM latency (~900cy).
// Rounds 15/16 staged A at distance 1 (~300-600cy before the gate) -> per-tile HBM-latency
// stall on the streaming A operand; this removes it. LDS = A 3x32K + B 2x32K = 160 KB.
// Tail: vmcnt(0) only at tile NT-2. Prologue A0,B0,A1,B1 -> vmcnt(8) retires A0,B0.
// SWZ: 0 = natural (gx%8==0 pins B-col panels/XCD), 1 = bijective chunk (z-slice/XCD).
// Rows 128 B; granule(16B) swizzle g^=(row&7); stage writes linear, inverse swizzle on
// the GLOBAL source col. OMODE: 0=f32, 1=f16, 2=f16 exp(v*scale), 3=f16 v*rcp(aux[z*2048+row]).
template <int OMODE, bool BIAS, bool SWZ>
__global__ __launch_bounds__(512, 2)
void gemm256(const _Float16* __restrict__ A, const _Float16* __restrict__ B,
             void* __restrict__ Cv, const float* __restrict__ aux, float scale,
             int K, int lda, int ldb, int ldc, int zmod,
             long a1, long a2, long b1, long b2, long c1, long c2) {
    __shared__ char lds[163840];
    int sbx, sby, sbz;
    if (SWZ) {
        const int gx = gridDim.x, gy = gridDim.y;
        const int nwg = gx * gy * gridDim.z;
        const int orig = (blockIdx.z * gy + blockIdx.y) * gx + blockIdx.x;
        const int q8 = nwg >> 3, r8 = nwg & 7;
        const int xcd = orig & 7, sub = orig >> 3;
        const int wgid = (xcd < r8 ? xcd * (q8 + 1) : r8 * (q8 + 1) + (xcd - r8) * q8) + sub;
        sbx = wgid % gx;
        const int tmp = wgid / gx;
        sby = tmp % gy; sbz = tmp / gy;
    } else {
        sbx = blockIdx.x; sby = blockIdx.y; sbz = blockIdx.z;
    }

    const int z = sbz, zq = z / zmod, zr = z - zq * zmod;
    A += zq * a1 + zr * a2;
    B += zq * b1 + zr * b2;
    const long coff = zq * c1 + zr * c2;
    const int tm = sby * 256, tn = sbx * 256;
    const int t = threadIdx.x;
    const int lane = t & 63, wid = t >> 6;
    const int wr = wid >> 2, wc = wid & 3;     // wave tile: rows wr*128, cols wc*64
    const int fr = lane & 15, kg = lane >> 4;

    // staging source (inverse-swizzled global col)
    const int strow = wid * 16 + (lane >> 3);
    const int stcol = ((lane & 7) ^ (lane >> 3)) * 8;
    const _Float16* gA = A + (long)(tm + strow) * lda + stcol;
    const _Float16* gB = B + (long)(tn + strow) * ldb + stcol;
    const int ldsw = wid * 2048;               // wave's linear chunk within each 16KB half

    // ds_read swizzled granule offsets (per lane, k-half h in {0,1})
    const int sw0 = 16 * ((0 * 4 + kg) ^ (fr & 7));
    const int sw1 = 16 * ((1 * 4 + kg) ^ (fr & 7));
    const int arowo = (wr * 128 + fr) * 128;   // byte row base within A slot
    const int browo = (wc * 64 + fr) * 128;    // byte row base within B slot

    const int NT = K >> 6;
    f32x4 acc[8][4] = {};

    auto stageA = [&](int tt, int h) {
        const _Float16* s = gA + (long)(h * 128) * lda + tt * 64;
        char* d = lds + (tt % 3) * 32768 + h * 16384 + ldsw;
        gload_lds16(s, d);
        gload_lds16(s + (long)8 * lda, d + 1024);
    };
    auto stageB = [&](int tt, int h) {
        const _Float16* s = gB + (long)(h * 128) * ldb + tt * 64;
        char* d = lds + 98304 + (tt & 1) * 32768 + h * 16384 + ldsw;
        gload_lds16(s, d);
        gload_lds16(s + (long)8 * ldb, d + 1024);
    };

    // prologue: A(0), B(0), A(1), B(1); gate vmcnt(8) retires A(0),B(0)
    stageA(0, 0); stageA(0, 1);
    stageB(0, 0); stageB(0, 1);
    stageA(1, 0); stageA(1, 1);
    stageB(1, 0); stageB(1, 1);
    asm volatile("s_waitcnt vmcnt(8)" ::: "memory");
    barrier_fenced();

    f16x8 bf0[2][2], bf1[2][2];

    for (int g = 0; g < NT; ++g) {
        const char* abuf = lds + (g % 3) * 32768;
        const char* bbuf = lds + 98304 + (g & 1) * 32768;
        // ---- half A: quadrants Q(0,0) + Q(0,1); stage A(g+2) into A slot (g+2)%3
        //      (that slot was last read in tile g-1, closed by this tile's start barrier)
        f16x8 af0[4][2];
#pragma unroll
        for (int m = 0; m < 4; ++m) {
            af0[m][0] = *(const f16x8*)(abuf + arowo + m * 2048 + sw0);
            af0[m][1] = *(const f16x8*)(abuf + arowo + m * 2048 + sw1);
        }
#pragma unroll
        for (int n = 0; n < 2; ++n) {
            bf0[n][0] = *(const f16x8*)(bbuf + browo + n * 2048 + sw0);
            bf0[n][1] = *(const f16x8*)(bbuf + browo + n * 2048 + sw1);
            bf1[n][0] = *(const f16x8*)(bbuf + browo + 4096 + n * 2048 + sw0);
            bf1[n][1] = *(const f16x8*)(bbuf + browo + 4096 + n * 2048 + sw1);
        }
        if (g + 2 < NT) { stageA(g + 2, 0); stageA(g + 2, 1); }
        __builtin_amdgcn_s_setprio(1);
#pragma unroll
        for (int m = 0; m < 4; ++m)
#pragma unroll
            for (int n = 0; n < 2; ++n)
#pragma unroll
                for (int k = 0; k < 2; ++k) {
                    acc[m][n]     = __builtin_amdgcn_mfma_f32_16x16x32_f16(af0[m][k], bf0[n][k], acc[m][n], 0, 0, 0);
                    acc[m][n + 2] = __builtin_amdgcn_mfma_f32_16x16x32_f16(af0[m][k], bf1[n][k], acc[m][n + 2], 0, 0, 0);
                }
        __builtin_amdgcn_s_setprio(0);
        barrier_fenced();   // closes all B reads: B(g+2) may now overwrite this parity's B slot
        // ---- half B: quadrants Q(1,1) + Q(1,0); stage B(g+2) into B slot (g+2)&1
        f16x8 af1[4][2];
#pragma unroll
        for (int m = 0; m < 4; ++m) {
            af1[m][0] = *(const f16x8*)(abuf + arowo + 8192 + m * 2048 + sw0);
            af1[m][1] = *(const f16x8*)(abuf + arowo + 8192 + m * 2048 + sw1);
        }
        if (g + 2 < NT) { stageB(g + 2, 0); stageB(g + 2, 1); }
        __builtin_amdgcn_s_setprio(1);
#pragma unroll
        for (int m = 0; m < 4; ++m)
#pragma unroll
            for (int n = 0; n < 2; ++n)
#pragma unroll
                for (int k = 0; k < 2; ++k) {
                    acc[m + 4][n + 2] = __builtin_amdgcn_mfma_f32_16x16x32_f16(af1[m][k], bf1[n][k], acc[m + 4][n + 2], 0, 0, 0);
                    acc[m + 4][n]     = __builtin_amdgcn_mfma_f32_16x16x32_f16(af1[m][k], bf0[n][k], acc[m + 4][n], 0, 0, 0);
                }
        __builtin_amdgcn_s_setprio(0);
        // ---- gate for tile g+1: retire A(g+1)+B(g+1) (issued a full tile earlier);
        //      A(g+2)+B(g+2) stay in flight (8). Drain only at the tail.
        if (g + 2 < NT)      asm volatile("s_waitcnt vmcnt(8)" ::: "memory");
        else if (g + 1 < NT) asm volatile("s_waitcnt vmcnt(0)" ::: "memory");
        barrier_fenced();
    }

    // epilogue: C/D layout col = lane&15, row = (lane>>4)*4 + r
    const int rb = tm + wr * 128 + (lane >> 4) * 4;
    const int cb = tn + wc * 64 + fr;
    const float* auxz = (OMODE == 3) ? (aux + (long)z * 2048) : aux;
#pragma unroll
    for (int m = 0; m < 8; ++m) {
#pragma unroll
        for (int r = 0; r < 4; ++r) {
            const int row = rb + m * 16 + r;
            float inv = 1.0f;
            if (OMODE == 3) inv = __builtin_amdgcn_rcpf(auxz[row]);
#pragma unroll
            for (int n = 0; n < 4; ++n) {
                float v = acc[m][n][r];
                const int col = cb + n * 16;
                if (BIAS) v += aux[col];
                if (OMODE == 0) {
                    ((float*)Cv)[coff + (long)row * ldc + col] = v;
                } else {
                    if (OMODE == 2) v = __expf(v * scale);
                    if (OMODE == 3) v *= inv;
                    ((_Float16*)Cv)[coff + (long)row * ldc + col] = (_Float16)v;
                }
            }
        }
    }
}

extern "C" void kernel_launch(void* const* d_in, const int* in_sizes, int n_in,
                              void* d_out, int out_size, void* d_ws, size_t ws_size,
                              hipStream_t stream) {
    const float* x    = (const float*)d_in[0];   // (4,2048,2048)
    const float* wqkv = (const float*)d_in[1];   // (2048,6144)
    const float* wout = (const float*)d_in[2];   // (2048,2048)
    const float* bout = (const float*)d_in[3];   // (2048,)
    char* ws = (char*)d_ws;

    _Float16* qkv_h = (_Float16*)(ws);
    _Float16* x_h   = (_Float16*)(ws + 100663296);
    _Float16* wqkvT = (_Float16*)(ws + 134217728);
    _Float16* vT    = (_Float16*)(ws + 100663296);
    float*    cosT  = (float*)(ws + 100663296);   // alias: lives between QKV GEMM and v_transpose
    float*    sinT  = (float*)(ws + 104857600);
    _Float16* woutT = (_Float16*)(ws);
    const bool batched = ws_size >= 234946560ULL;  // incl. 64KB rowsum buffer

    // 1. x -> f16
    f32_to_f16_vec<<<dim3(16384), dim3(256), 0, stream>>>(x, x_h);
    // 2. wqkv (2048x6144) -> wqkvT (6144x2048) f16
    transpose_f32_to_f16<<<dim3(192, 64), dim3(256), 0, stream>>>(wqkv, wqkvT, 2048, 6144);
    // 3. qkv = x @ wqkv  (M=8192,N=6144,K=2048) -> f16  [natural order: XCD = bx%8 pins B cols]
    gemm256<1, false, false><<<dim3(24, 32, 1), dim3(512), 0, stream>>>(
        x_h, wqkvT, (void*)qkv_h, nullptr, 0.f, 2048, 2048, 2048, 6144,
        1, 0L, 0L, 0L, 0L, 0L, 0L);
    // 4. RoPE tables (x_h now dead; tables alias that region)
    rope_tables_k<<<dim3(4096), dim3(256), 0, stream>>>(cosT, sinT);
    // 5. RoPE in place on q,k halves (head-mixing rotation)
    rope_inplace<<<dim3(8192), dim3(256), 0, stream>>>(qkv_h, cosT, sinT);
    // 6. V transpose -> vT (b,h,d,s)  (overwrites table region; tables dead)
    v_transpose<<<dim3(64, 32, 8), dim3(256), 0, stream>>>(qkv_h, vT);

    if (batched) {
        _Float16* S16  = (_Float16*)(ws + 134217728);
        _Float16* aout = (_Float16*)(ws + 201326592);
        float*    lsum = (float*)(ws + 234881024);   // 8*2048 f32
        // 7. S~ = exp(scale * Q@K^T), all 8 (b,h)  [SWZ: one z-slice per XCD]
        gemm256<2, false, true><<<dim3(8, 8, 8), dim3(512), 0, stream>>>(
            qkv_h, qkv_h + 2048, (void*)S16, nullptr, 0.03125f, 1024, 6144, 6144, 2048,
            2, 12582912L, 1024L, 12582912L, 1024L, 8388608L, 4194304L);
        // 8. row sums of S~
        rowsum_f16<<<dim3(4096), dim3(256), 0, stream>>>(S16, lsum);
        // 9. O = (S~ @ V) / l  [SWZ: one z-slice per XCD]
        gemm256<3, false, true><<<dim3(4, 8, 8), dim3(512), 0, stream>>>(
            S16, vT, (void*)aout, lsum, 0.f, 2048, 2048, 2048, 2048,
            2, 8388608L, 4194304L, 4194304L, 2097152L, 4194304L, 1024L);
        // 10. wout -> woutT; out = aout @ wout + bout  [natural order]
        transpose_f32_to_f16<<<dim3(64, 64), dim3(256), 0, stream>>>(wout, woutT, 2048, 2048);
        gemm256<0, true, false><<<dim3(8, 32, 1), dim3(512), 0, stream>>>(
            aout, woutT, d_out, bout, 0.f, 2048, 2048, 2048, 2048,
            1, 0L, 0L, 0L, 0L, 0L, 0L);
    } else {
        float*    S32  = (float*)(ws + 134217728);
        _Float16* aout = (_Float16*)(ws + 150994944);
        for (int z = 0; z < 8; ++z) {
            const _Float16* Az = qkv_h + (long)(z >> 1) * 12582912 + (z & 1) * 1024;
            gemm256<0, false, false><<<dim3(8, 8, 1), dim3(512), 0, stream>>>(
                Az, Az + 2048, (void*)S32, nullptr, 0.f, 1024, 6144, 6144, 2048,
                1, 0L, 0L, 0L, 0L, 0L, 0L);
            softmax_rows_f32<<<dim3(512), dim3(256), 0, stream>>>(S32, 0.03125f);
            gemm256<1, false, false><<<dim3(4, 8, 1), dim3(512), 0, stream>>>(
                (const _Float16*)S32, vT + (long)z * 2097152,
                (void*)(aout + (long)(z >> 1) * 4194304 + (z & 1) * 1024), nullptr, 0.f,
                2048, 4096, 2048, 2048, 1, 0L, 0L, 0L, 0L, 0L, 0L);
        }
        transpose_f32_to_f16<<<dim3(64, 64), dim3(256), 0, stream>>>(wout, woutT, 2048, 2048);
        gemm256<0, true, false><<<dim3(8, 32, 1), dim3(512), 0, stream>>>(
            aout, woutT, d_out, bout, 0.f, 2048, 2048, 2048, 2048,
            1, 0L, 0L, 0L, 0L, 0L, 0L);
    }
}

// Round 18
// 486.382 us; speedup vs baseline: 1.0012x; 1.0012x over previous
//
#include <hip/hip_runtime.h>
#include <hip/hip_fp16.h>

typedef __attribute__((ext_vector_type(4))) float f32x4;
typedef __attribute__((ext_vector_type(8))) _Float16 f16x8;
typedef __attribute__((ext_vector_type(4))) _Float16 f16x4;

// ---------------- helpers ----------------
__device__ __forceinline__ void gload_lds16(const void* gp, void* lp) {
    __builtin_amdgcn_global_load_lds(
        (const __attribute__((address_space(1))) void*)gp,
        (__attribute__((address_space(3))) void*)lp, 16, 0, 0);
}

// Barrier as inline asm WITH memory clobber: raw __builtin_amdgcn_s_barrier() is
// IntrNoMem in LLVM, so LDS/global ops can be reordered across it (round-7 race).
__device__ __forceinline__ void barrier_fenced() {
    asm volatile("s_barrier" ::: "memory");
}

// ---------------- RoPE tables: cos/sin (2048 x 512) f32 ----------------
__global__ void rope_tables_k(float* __restrict__ cosT, float* __restrict__ sinT) {
    int idx = blockIdx.x * 256 + threadIdx.x;
    int s = idx >> 9, j = idx & 511;
    float invf = exp2f(-13.287712379549449f * (float)j * (1.0f / 512.0f)); // 10000^(-j/512)
    float ang = (float)s * invf;
    float sn, cs;
    sincosf(ang, &sn, &cs);
    cosT[idx] = cs;
    sinT[idx] = sn;
}

// ---------------- f32 -> f16 straight convert ----------------
__global__ void f32_to_f16_vec(const float* __restrict__ in, _Float16* __restrict__ out) {
    long i = ((long)blockIdx.x * 256 + threadIdx.x) * 4;
    f32x4 v = *(const f32x4*)(in + i);
    f16x4 h;
#pragma unroll
    for (int e = 0; e < 4; ++e) h[e] = (_Float16)v[e];
    *(f16x4*)(out + i) = h;
}

// ---------------- transpose + convert: in (R x C) f32 -> out (C x R) f16 ----------------
__global__ void transpose_f32_to_f16(const float* __restrict__ in, _Float16* __restrict__ out,
                                     int R, int C) {
    __shared__ _Float16 tile[32][36];
    const int c0 = blockIdx.x * 32, r0 = blockIdx.y * 32;
    const int t = threadIdx.x;
    const int r = t >> 3, c4 = (t & 7) * 4;
    f32x4 v = *(const f32x4*)(in + (long)(r0 + r) * C + c0 + c4);
    f16x4 h;
#pragma unroll
    for (int e = 0; e < 4; ++e) h[e] = (_Float16)v[e];
    *(f16x4*)&tile[r][c4] = h;
    __syncthreads();
    const int oc = t >> 3, o4 = (t & 7) * 4;
    f16x4 o;
#pragma unroll
    for (int e = 0; e < 4; ++e) o[e] = tile[o4 + e][oc];
    *(f16x4*)(out + (long)(c0 + oc) * R + r0 + o4) = o;
}

// ---------------- RoPE in-place on qkv rows (head-mixing: pair j with j+1024) ----------------
__global__ void rope_inplace(_Float16* __restrict__ qkv, const float* __restrict__ cosT,
                             const float* __restrict__ sinT) {
    const int row = blockIdx.x;            // b*2048 + s
    const int s = row & 2047;
    const int j0 = threadIdx.x * 4;        // [0,1024)
    _Float16* base = qkv + (long)row * 6144;
    f16x4 q0 = *(const f16x4*)(base + j0);
    f16x4 q1 = *(const f16x4*)(base + 1024 + j0);
    f16x4 k0 = *(const f16x4*)(base + 2048 + j0);
    f16x4 k1 = *(const f16x4*)(base + 3072 + j0);
    const int jj = j0 & 511;
    f32x4 cs = *(const f32x4*)(cosT + (long)s * 512 + jj);
    f32x4 sn = *(const f32x4*)(sinT + (long)s * 512 + jj);
    f16x4 oq0, oq1, ok0, ok1;
#pragma unroll
    for (int e = 0; e < 4; ++e) {
        float a = (float)q0[e], b = (float)q1[e];
        oq0[e] = (_Float16)(a * cs[e] - b * sn[e]);
        oq1[e] = (_Float16)(b * cs[e] + a * sn[e]);
        float c = (float)k0[e], d = (float)k1[e];
        ok0[e] = (_Float16)(c * cs[e] - d * sn[e]);
        ok1[e] = (_Float16)(d * cs[e] + c * sn[e]);
    }
    *(f16x4*)(base + j0) = oq0;
    *(f16x4*)(base + 1024 + j0) = oq1;
    *(f16x4*)(base + 2048 + j0) = ok0;
    *(f16x4*)(base + 3072 + j0) = ok1;
}

// ---------------- V transpose: qkv v-part (b,s,h,d) -> vT (b,h,d,s) f16 ----------------
__global__ void v_transpose(const _Float16* __restrict__ qkv, _Float16* __restrict__ vT) {
    __shared__ _Float16 tile[32][36];
    const int z = blockIdx.z, b = z >> 1, h = z & 1;
    const int s0 = blockIdx.x * 32, d0 = blockIdx.y * 32;
    const int t = threadIdx.x;
    const int r = t >> 3, c4 = (t & 7) * 4;
    const _Float16* src = qkv + (long)(b * 2048 + s0 + r) * 6144 + 4096 + h * 1024 + d0 + c4;
    *(f16x4*)&tile[r][c4] = *(const f16x4*)src;
    __syncthreads();
    const int dr = t >> 3, sc = (t & 7) * 4;
    f16x4 o;
#pragma unroll
    for (int e = 0; e < 4; ++e) o[e] = tile[sc + e][dr];
    *(f16x4*)(vT + ((long)z * 1024 + d0 + dr) * 2048 + s0 + sc) = o;
}

// ---------------- softmax on f32 rows (2048), writes f16 P in place (fallback path) ----------------
__global__ __launch_bounds__(256) void softmax_rows_f32(float* __restrict__ S, float scale) {
    const int wid = threadIdx.x >> 6, lane = threadIdx.x & 63;
    const long row = (long)blockIdx.x * 4 + wid;
    float* rp = S + row * 2048;
    f32x4 v[8];
    float mx = -1e30f;
#pragma unroll
    for (int i = 0; i < 8; ++i) {
        v[i] = *(const f32x4*)(rp + (i * 64 + lane) * 4);
#pragma unroll
        for (int e = 0; e < 4; ++e) mx = fmaxf(mx, v[i][e]);
    }
#pragma unroll
    for (int o = 32; o > 0; o >>= 1) mx = fmaxf(mx, __shfl_xor(mx, o, 64));
    float sum = 0.f;
#pragma unroll
    for (int i = 0; i < 8; ++i)
#pragma unroll
        for (int e = 0; e < 4; ++e) {
            float p = __expf(scale * (v[i][e] - mx));
            v[i][e] = p; sum += p;
        }
#pragma unroll
    for (int o = 32; o > 0; o >>= 1) sum += __shfl_xor(sum, o, 64);
    float inv = 1.0f / sum;
    _Float16* wp = (_Float16*)S + row * 4096;
#pragma unroll
    for (int i = 0; i < 8; ++i) {
        f16x4 h;
#pragma unroll
        for (int e = 0; e < 4; ++e) h[e] = (_Float16)(v[i][e] * inv);
        *(f16x4*)(wp + (i * 64 + lane) * 4) = h;
    }
}

// ---------------- row-sum of f16 rows (2048 wide) -> f32 sums ----------------
__global__ __launch_bounds__(256) void rowsum_f16(const _Float16* __restrict__ S,
                                                  float* __restrict__ l) {
    const int wid = threadIdx.x >> 6, lane = threadIdx.x & 63;
    const long row = (long)blockIdx.x * 4 + wid;
    const _Float16* rp = S + row * 2048;
    float sum = 0.f;
#pragma unroll
    for (int i = 0; i < 4; ++i) {
        f16x8 v = *(const f16x8*)(rp + i * 512 + lane * 8);
#pragma unroll
        for (int e = 0; e < 8; ++e) sum += (float)v[e];
    }
#pragma unroll
    for (int o = 32; o > 0; o >>= 1) sum += __shfl_xor(sum, o, 64);
    if (lane == 0) l[row] = sum;
}

// ---------------- GEMM 256x256, BK=64, 8 waves, 2-buffer LDS, 2-barrier/K-tile schedule ----------------
// Round-15 structure (best measured: 483.6us total) + ONE change: the af1 (A upper-half)
// ds_reads are hoisted ABOVE the mid-tile barrier. They read tile-g's A region, which no
// in-flight stage touches there (A(g+1) targets the opposite parity; B(g+2) not yet issued),
// so the hoist is hazard-free; their ~120cy LDS latency then hides under the barrier wait and
// cluster 2 finds the data resident. Placed after cluster-1's setprio(0) so af1 liveness does
// not overlap cluster 1 (no VGPR growth).
// Per K-tile: 2 fenced barriers (mid-tile B-WAR close; end-of-tile gate w/ counted vmcnt(4)).
// vmcnt queue at gate: [A(g+1):4][B(g+2):4] -> vmcnt(4) retires A(g+1), leaves B(g+2).
// SWZ: 0 = natural mapping (gx%8==0 pins B-col panels per XCD; single-batch GEMMs),
//      1 = bijective chunk (m204; one z-slice per XCD; z-batched attention GEMMs).
// LDS per buffer: A 256x64 f16 [0,32K), B [32K,64K); rows 128 B; granule(16B) swizzle g^=(row&7),
// stage writes linear (global_load_lds), inverse swizzle on the GLOBAL source col.
// OMODE: 0 = f32 out, 1 = f16 out, 2 = f16 exp(v*scale), 3 = f16 v*rcp(aux[z*2048+row]).
template <int OMODE, bool BIAS, bool SWZ>
__global__ __launch_bounds__(512, 2)
void gemm256(const _Float16* __restrict__ A, const _Float16* __restrict__ B,
             void* __restrict__ Cv, const float* __restrict__ aux, float scale,
             int K, int lda, int ldb, int ldc, int zmod,
             long a1, long a2, long b1, long b2, long c1, long c2) {
    __shared__ char lds[131072];
    int sbx, sby, sbz;
    if (SWZ) {
        const int gx = gridDim.x, gy = gridDim.y;
        const int nwg = gx * gy * gridDim.z;
        const int orig = (blockIdx.z * gy + blockIdx.y) * gx + blockIdx.x;
        const int q8 = nwg >> 3, r8 = nwg & 7;
        const int xcd = orig & 7, sub = orig >> 3;
        const int wgid = (xcd < r8 ? xcd * (q8 + 1) : r8 * (q8 + 1) + (xcd - r8) * q8) + sub;
        sbx = wgid % gx;
        const int tmp = wgid / gx;
        sby = tmp % gy; sbz = tmp / gy;
    } else {
        sbx = blockIdx.x; sby = blockIdx.y; sbz = blockIdx.z;
    }

    const int z = sbz, zq = z / zmod, zr = z - zq * zmod;
    A += zq * a1 + zr * a2;
    B += zq * b1 + zr * b2;
    const long coff = zq * c1 + zr * c2;
    const int tm = sby * 256, tn = sbx * 256;
    const int t = threadIdx.x;
    const int lane = t & 63, wid = t >> 6;
    const int wr = wid >> 2, wc = wid & 3;     // wave tile: rows wr*128, cols wc*64
    const int fr = lane & 15, kg = lane >> 4;

    // staging source (inverse-swizzled global col)
    const int strow = wid * 16 + (lane >> 3);
    const int stcol = ((lane & 7) ^ (lane >> 3)) * 8;
    const _Float16* gA = A + (long)(tm + strow) * lda + stcol;
    const _Float16* gB = B + (long)(tn + strow) * ldb + stcol;
    char* const ldsw = lds + wid * 2048;       // wave's linear chunk base (+1024 for 2nd load)

    // ds_read swizzled granule offsets (per lane, k-half h in {0,1})
    const int sw0 = 16 * ((0 * 4 + kg) ^ (fr & 7));
    const int sw1 = 16 * ((1 * 4 + kg) ^ (fr & 7));

    const int NT = K >> 6;
    f32x4 acc[8][4] = {};

    auto stageA = [&](int tt, int h) {
        const _Float16* s = gA + (long)(h * 128) * lda + tt * 64;
        char* d = ldsw + (tt & 1) * 65536 + h * 16384;
        gload_lds16(s, d);
        gload_lds16(s + (long)8 * lda, d + 1024);
    };
    auto stageB = [&](int tt, int h) {
        const _Float16* s = gB + (long)(h * 128) * ldb + tt * 64;
        char* d = ldsw + (tt & 1) * 65536 + 32768 + h * 16384;
        gload_lds16(s, d);
        gload_lds16(s + (long)8 * ldb, d + 1024);
    };

    // prologue: B(0), A(0) -> buf0; B(1) -> buf1; gate tile0 (vmcnt(4) leaves B(1) in flight)
    stageB(0, 0); stageB(0, 1); stageA(0, 0); stageA(0, 1);
    stageB(1, 0); stageB(1, 1);
    asm volatile("s_waitcnt vmcnt(4)" ::: "memory");
    barrier_fenced();

    f16x8 bf0[2][2], bf1[2][2];
    const int arow = (wr * 128 + fr) * 128;          // byte row base for A frags
    const int brow = 32768 + (wc * 64 + fr) * 128;   // byte row base for B frags

    for (int g = 0; g < NT; ++g) {
        const char* buf = lds + (g & 1) * 65536;
        // ---- half A: quadrants Q(0,0) + Q(0,1); stage A(g+1) into buf^1
        f16x8 af0[4][2];
#pragma unroll
        for (int m = 0; m < 4; ++m) {
            af0[m][0] = *(const f16x8*)(buf + arow + m * 2048 + sw0);
            af0[m][1] = *(const f16x8*)(buf + arow + m * 2048 + sw1);
        }
#pragma unroll
        for (int n = 0; n < 2; ++n) {
            bf0[n][0] = *(const f16x8*)(buf + brow + n * 2048 + sw0);
            bf0[n][1] = *(const f16x8*)(buf + brow + n * 2048 + sw1);
            bf1[n][0] = *(const f16x8*)(buf + brow + 4096 + n * 2048 + sw0);
            bf1[n][1] = *(const f16x8*)(buf + brow + 4096 + n * 2048 + sw1);
        }
        if (g + 1 < NT) { stageA(g + 1, 0); stageA(g + 1, 1); }
        __builtin_amdgcn_s_setprio(1);
#pragma unroll
        for (int m = 0; m < 4; ++m)
#pragma unroll
            for (int n = 0; n < 2; ++n)
#pragma unroll
                for (int k = 0; k < 2; ++k) {
                    acc[m][n]     = __builtin_amdgcn_mfma_f32_16x16x32_f16(af0[m][k], bf0[n][k], acc[m][n], 0, 0, 0);
                    acc[m][n + 2] = __builtin_amdgcn_mfma_f32_16x16x32_f16(af0[m][k], bf1[n][k], acc[m][n + 2], 0, 0, 0);
                }
        __builtin_amdgcn_s_setprio(0);
        // ---- af1 reads HOISTED above the mid-tile barrier (A region of tile g is not
        //      written by any in-flight stage here) -> latency hides under the barrier wait
        f16x8 af1[4][2];
#pragma unroll
        for (int m = 0; m < 4; ++m) {
            af1[m][0] = *(const f16x8*)(buf + arow + 8192 + m * 2048 + sw0);
            af1[m][1] = *(const f16x8*)(buf + arow + 8192 + m * 2048 + sw1);
        }
        barrier_fenced();   // closes all B reads: B(g+2) may now overwrite current B region
        // ---- half B: quadrants Q(1,1) + Q(1,0); stage B(g+2) into current buf
        if (g + 2 < NT) { stageB(g + 2, 0); stageB(g + 2, 1); }
        __builtin_amdgcn_s_setprio(1);
#pragma unroll
        for (int m = 0; m < 4; ++m)
#pragma unroll
            for (int n = 0; n < 2; ++n)
#pragma unroll
                for (int k = 0; k < 2; ++k) {
                    acc[m + 4][n + 2] = __builtin_amdgcn_mfma_f32_16x16x32_f16(af1[m][k], bf1[n][k], acc[m + 4][n + 2], 0, 0, 0);
                    acc[m + 4][n]     = __builtin_amdgcn_mfma_f32_16x16x32_f16(af1[m][k], bf0[n][k], acc[m + 4][n], 0, 0, 0);
                }
        __builtin_amdgcn_s_setprio(0);
        // ---- gate for tile g+1 (counted; never drains mid-loop)
        if (g + 2 < NT)      asm volatile("s_waitcnt vmcnt(4)" ::: "memory");
        else if (g + 1 < NT) asm volatile("s_waitcnt vmcnt(0)" ::: "memory");
        barrier_fenced();   // also closes A reads before next tile's stages
    }

    // epilogue: C/D layout col = lane&15, row = (lane>>4)*4 + r
    const int rb = tm + wr * 128 + (lane >> 4) * 4;
    const int cb = tn + wc * 64 + fr;
    const float* auxz = (OMODE == 3) ? (aux + (long)z * 2048) : aux;
#pragma unroll
    for (int m = 0; m < 8; ++m) {
#pragma unroll
        for (int r = 0; r < 4; ++r) {
            const int row = rb + m * 16 + r;
            float inv = 1.0f;
            if (OMODE == 3) inv = __builtin_amdgcn_rcpf(auxz[row]);
#pragma unroll
            for (int n = 0; n < 4; ++n) {
                float v = acc[m][n][r];
                const int col = cb + n * 16;
                if (BIAS) v += aux[col];
                if (OMODE == 0) {
                    ((float*)Cv)[coff + (long)row * ldc + col] = v;
                } else {
                    if (OMODE == 2) v = __expf(v * scale);
                    if (OMODE == 3) v *= inv;
                    ((_Float16*)Cv)[coff + (long)row * ldc + col] = (_Float16)v;
                }
            }
        }
    }
}

extern "C" void kernel_launch(void* const* d_in, const int* in_sizes, int n_in,
                              void* d_out, int out_size, void* d_ws, size_t ws_size,
                              hipStream_t stream) {
    const float* x    = (const float*)d_in[0];   // (4,2048,2048)
    const float* wqkv = (const float*)d_in[1];   // (2048,6144)
    const float* wout = (const float*)d_in[2];   // (2048,2048)
    const float* bout = (const float*)d_in[3];   // (2048,)
    char* ws = (char*)d_ws;

    _Float16* qkv_h = (_Float16*)(ws);
    _Float16* x_h   = (_Float16*)(ws + 100663296);
    _Float16* wqkvT = (_Float16*)(ws + 134217728);
    _Float16* vT    = (_Float16*)(ws + 100663296);
    float*    cosT  = (float*)(ws + 100663296);   // alias: lives between QKV GEMM and v_transpose
    float*    sinT  = (float*)(ws + 104857600);
    _Float16* woutT = (_Float16*)(ws);
    const bool batched = ws_size >= 234946560ULL;  // incl. 64KB rowsum buffer

    // 1. x -> f16
    f32_to_f16_vec<<<dim3(16384), dim3(256), 0, stream>>>(x, x_h);
    // 2. wqkv (2048x6144) -> wqkvT (6144x2048) f16
    transpose_f32_to_f16<<<dim3(192, 64), dim3(256), 0, stream>>>(wqkv, wqkvT, 2048, 6144);
    // 3. qkv = x @ wqkv  (M=8192,N=6144,K=2048) -> f16  [natural order: XCD = bx%8 pins B cols]
    gemm256<1, false, false><<<dim3(24, 32, 1), dim3(512), 0, stream>>>(
        x_h, wqkvT, (void*)qkv_h, nullptr, 0.f, 2048, 2048, 2048, 6144,
        1, 0L, 0L, 0L, 0L, 0L, 0L);
    // 4. RoPE tables (x_h now dead; tables alias that region)
    rope_tables_k<<<dim3(4096), dim3(256), 0, stream>>>(cosT, sinT);
    // 5. RoPE in place on q,k halves (head-mixing rotation)
    rope_inplace<<<dim3(8192), dim3(256), 0, stream>>>(qkv_h, cosT, sinT);
    // 6. V transpose -> vT (b,h,d,s)  (overwrites table region; tables dead)
    v_transpose<<<dim3(64, 32, 8), dim3(256), 0, stream>>>(qkv_h, vT);

    if (batched) {
        _Float16* S16  = (_Float16*)(ws + 134217728);
        _Float16* aout = (_Float16*)(ws + 201326592);
        float*    lsum = (float*)(ws + 234881024);   // 8*2048 f32
        // 7. S~ = exp(scale * Q@K^T), all 8 (b,h)  [SWZ: one z-slice per XCD]
        gemm256<2, false, true><<<dim3(8, 8, 8), dim3(512), 0, stream>>>(
            qkv_h, qkv_h + 2048, (void*)S16, nullptr, 0.03125f, 1024, 6144, 6144, 2048,
            2, 12582912L, 1024L, 12582912L, 1024L, 8388608L, 4194304L);
        // 8. row sums of S~
        rowsum_f16<<<dim3(4096), dim3(256), 0, stream>>>(S16, lsum);
        // 9. O = (S~ @ V) / l  [SWZ: one z-slice per XCD]
        gemm256<3, false, true><<<dim3(4, 8, 8), dim3(512), 0, stream>>>(
            S16, vT, (void*)aout, lsum, 0.f, 2048, 2048, 2048, 2048,
            2, 8388608L, 4194304L, 4194304L, 2097152L, 4194304L, 1024L);
        // 10. wout -> woutT; out = aout @ wout + bout  [natural order]
        transpose_f32_to_f16<<<dim3(64, 64), dim3(256), 0, stream>>>(wout, woutT, 2048, 2048);
        gemm256<0, true, false><<<dim3(8, 32, 1), dim3(512), 0, stream>>>(
            aout, woutT, d_out, bout, 0.f, 2048, 2048, 2048, 2048,
            1, 0L, 0L, 0L, 0L, 0L, 0L);
    } else {
        float*    S32  = (float*)(ws + 134217728);
        _Float16* aout = (_Float16*)(ws + 150994944);
        for (int z = 0; z < 8; ++z) {
            const _Float16* Az = qkv_h + (long)(z >> 1) * 12582912 + (z & 1) * 1024;
            gemm256<0, false, false><<<dim3(8, 8, 1), dim3(512), 0, stream>>>(
                Az, Az + 2048, (void*)S32, nullptr, 0.f, 1024, 6144, 6144, 2048,
                1, 0L, 0L, 0L, 0L, 0L, 0L);
            softmax_rows_f32<<<dim3(512), dim3(256), 0, stream>>>(S32, 0.03125f);
            gemm256<1, false, false><<<dim3(4, 8, 1), dim3(512), 0, stream>>>(
                (const _Float16*)S32, vT + (long)z * 2097152,
                (void*)(aout + (long)(z >> 1) * 4194304 + (z & 1) * 1024), nullptr, 0.f,
                2048, 4096, 2048, 2048, 1, 0L, 0L, 0L, 0L, 0L, 0L);
        }
        transpose_f32_to_f16<<<dim3(64, 64), dim3(256), 0, stream>>>(wout, woutT, 2048, 2048);
        gemm256<0, true, false><<<dim3(8, 32, 1), dim3(512), 0, stream>>>(
            aout, woutT, d_out, bout, 0.f, 2048, 2048, 2048, 2048,
            1, 0L, 0L, 0L, 0L, 0L, 0L);
    }
}

// Round 19
// 485.405 us; speedup vs baseline: 1.0032x; 1.0020x over previous
//
#include <hip/hip_runtime.h>
#include <hip/hip_fp16.h>

typedef __attribute__((ext_vector_type(4))) float f32x4;
typedef __attribute__((ext_vector_type(8))) _Float16 f16x8;
typedef __attribute__((ext_vector_type(4))) _Float16 f16x4;

// ---------------- helpers ----------------
__device__ __forceinline__ void gload_lds16(const void* gp, void* lp) {
    __builtin_amdgcn_global_load_lds(
        (const __attribute__((address_space(1))) void*)gp,
        (__attribute__((address_space(3))) void*)lp, 16, 0, 0);
}

// Barrier as inline asm WITH memory clobber: raw __builtin_amdgcn_s_barrier() is
// IntrNoMem in LLVM, so LDS/global ops can be reordered across it (round-7 race).
__device__ __forceinline__ void barrier_fenced() {
    asm volatile("s_barrier" ::: "memory");
}

// ---------------- RoPE tables: cos/sin (2048 x 512) f32 ----------------
__global__ void rope_tables_k(float* __restrict__ cosT, float* __restrict__ sinT) {
    int idx = blockIdx.x * 256 + threadIdx.x;
    int s = idx >> 9, j = idx & 511;
    float invf = exp2f(-13.287712379549449f * (float)j * (1.0f / 512.0f)); // 10000^(-j/512)
    float ang = (float)s * invf;
    float sn, cs;
    sincosf(ang, &sn, &cs);
    cosT[idx] = cs;
    sinT[idx] = sn;
}

// ---------------- f32 -> f16 straight convert ----------------
__global__ void f32_to_f16_vec(const float* __restrict__ in, _Float16* __restrict__ out) {
    long i = ((long)blockIdx.x * 256 + threadIdx.x) * 4;
    f32x4 v = *(const f32x4*)(in + i);
    f16x4 h;
#pragma unroll
    for (int e = 0; e < 4; ++e) h[e] = (_Float16)v[e];
    *(f16x4*)(out + i) = h;
}

// ---------------- transpose + convert: in (R x C) f32 -> out (C x R) f16 ----------------
__global__ void transpose_f32_to_f16(const float* __restrict__ in, _Float16* __restrict__ out,
                                     int R, int C) {
    __shared__ _Float16 tile[32][36];
    const int c0 = blockIdx.x * 32, r0 = blockIdx.y * 32;
    const int t = threadIdx.x;
    const int r = t >> 3, c4 = (t & 7) * 4;
    f32x4 v = *(const f32x4*)(in + (long)(r0 + r) * C + c0 + c4);
    f16x4 h;
#pragma unroll
    for (int e = 0; e < 4; ++e) h[e] = (_Float16)v[e];
    *(f16x4*)&tile[r][c4] = h;
    __syncthreads();
    const int oc = t >> 3, o4 = (t & 7) * 4;
    f16x4 o;
#pragma unroll
    for (int e = 0; e < 4; ++e) o[e] = tile[o4 + e][oc];
    *(f16x4*)(out + (long)(c0 + oc) * R + r0 + o4) = o;
}

// ---------------- RoPE in-place on qkv rows (head-mixing: pair j with j+1024) ----------------
__global__ void rope_inplace(_Float16* __restrict__ qkv, const float* __restrict__ cosT,
                             const float* __restrict__ sinT) {
    const int row = blockIdx.x;            // b*2048 + s
    const int s = row & 2047;
    const int j0 = threadIdx.x * 4;        // [0,1024)
    _Float16* base = qkv + (long)row * 6144;
    f16x4 q0 = *(const f16x4*)(base + j0);
    f16x4 q1 = *(const f16x4*)(base + 1024 + j0);
    f16x4 k0 = *(const f16x4*)(base + 2048 + j0);
    f16x4 k1 = *(const f16x4*)(base + 3072 + j0);
    const int jj = j0 & 511;
    f32x4 cs = *(const f32x4*)(cosT + (long)s * 512 + jj);
    f32x4 sn = *(const f32x4*)(sinT + (long)s * 512 + jj);
    f16x4 oq0, oq1, ok0, ok1;
#pragma unroll
    for (int e = 0; e < 4; ++e) {
        float a = (float)q0[e], b = (float)q1[e];
        oq0[e] = (_Float16)(a * cs[e] - b * sn[e]);
        oq1[e] = (_Float16)(b * cs[e] + a * sn[e]);
        float c = (float)k0[e], d = (float)k1[e];
        ok0[e] = (_Float16)(c * cs[e] - d * sn[e]);
        ok1[e] = (_Float16)(d * cs[e] + c * sn[e]);
    }
    *(f16x4*)(base + j0) = oq0;
    *(f16x4*)(base + 1024 + j0) = oq1;
    *(f16x4*)(base + 2048 + j0) = ok0;
    *(f16x4*)(base + 3072 + j0) = ok1;
}

// ---------------- V transpose: qkv v-part (b,s,h,d) -> vT (b,h,d,s) f16 ----------------
__global__ void v_transpose(const _Float16* __restrict__ qkv, _Float16* __restrict__ vT) {
    __shared__ _Float16 tile[32][36];
    const int z = blockIdx.z, b = z >> 1, h = z & 1;
    const int s0 = blockIdx.x * 32, d0 = blockIdx.y * 32;
    const int t = threadIdx.x;
    const int r = t >> 3, c4 = (t & 7) * 4;
    const _Float16* src = qkv + (long)(b * 2048 + s0 + r) * 6144 + 4096 + h * 1024 + d0 + c4;
    *(f16x4*)&tile[r][c4] = *(const f16x4*)src;
    __syncthreads();
    const int dr = t >> 3, sc = (t & 7) * 4;
    f16x4 o;
#pragma unroll
    for (int e = 0; e < 4; ++e) o[e] = tile[sc + e][dr];
    *(f16x4*)(vT + ((long)z * 1024 + d0 + dr) * 2048 + s0 + sc) = o;
}

// ---------------- softmax on f32 rows (2048), writes f16 P in place (fallback path) ----------------
__global__ __launch_bounds__(256) void softmax_rows_f32(float* __restrict__ S, float scale) {
    const int wid = threadIdx.x >> 6, lane = threadIdx.x & 63;
    const long row = (long)blockIdx.x * 4 + wid;
    float* rp = S + row * 2048;
    f32x4 v[8];
    float mx = -1e30f;
#pragma unroll
    for (int i = 0; i < 8; ++i) {
        v[i] = *(const f32x4*)(rp + (i * 64 + lane) * 4);
#pragma unroll
        for (int e = 0; e < 4; ++e) mx = fmaxf(mx, v[i][e]);
    }
#pragma unroll
    for (int o = 32; o > 0; o >>= 1) mx = fmaxf(mx, __shfl_xor(mx, o, 64));
    float sum = 0.f;
#pragma unroll
    for (int i = 0; i < 8; ++i)
#pragma unroll
        for (int e = 0; e < 4; ++e) {
            float p = __expf(scale * (v[i][e] - mx));
            v[i][e] = p; sum += p;
        }
#pragma unroll
    for (int o = 32; o > 0; o >>= 1) sum += __shfl_xor(sum, o, 64);
    float inv = 1.0f / sum;
    _Float16* wp = (_Float16*)S + row * 4096;
#pragma unroll
    for (int i = 0; i < 8; ++i) {
        f16x4 h;
#pragma unroll
        for (int e = 0; e < 4; ++e) h[e] = (_Float16)(v[i][e] * inv);
        *(f16x4*)(wp + (i * 64 + lane) * 4) = h;
    }
}

// ---------------- row-sum of f16 rows (2048 wide) -> f32 sums ----------------
__global__ __launch_bounds__(256) void rowsum_f16(const _Float16* __restrict__ S,
                                                  float* __restrict__ l) {
    const int wid = threadIdx.x >> 6, lane = threadIdx.x & 63;
    const long row = (long)blockIdx.x * 4 + wid;
    const _Float16* rp = S + row * 2048;
    float sum = 0.f;
#pragma unroll
    for (int i = 0; i < 4; ++i) {
        f16x8 v = *(const f16x8*)(rp + i * 512 + lane * 8);
#pragma unroll
        for (int e = 0; e < 8; ++e) sum += (float)v[e];
    }
#pragma unroll
    for (int o = 32; o > 0; o >>= 1) sum += __shfl_xor(sum, o, 64);
    if (lane == 0) l[row] = sum;
}

// ---------------- GEMM 256x256, BK=64, 8 waves, 2-buffer LDS, 2-barrier/K-tile schedule ----------------
// BEST MEASURED CONFIG (round 15, 483.6us total; rounds 16-18 variants all neutral/worse):
// per K-tile only the 2 load-bearing barriers:
//  (1) mid-tile (closes all B-fragment reads before B(g+2) overwrites current buf's B region),
//  (2) tile-end gate (counted vmcnt(4) + barrier; orders stages -> next tile's reads).
// Waves slide within a half-tile so one wave's ds_reads overlap its SIMD-partner's MFMAs;
// per-wave compiler-inserted lgkmcnt keeps RAW within a wave.
// vmcnt queue at gate: [A(g+1):4][B(g+2):4] -> vmcnt(4) retires A(g+1), leaves B(g+2).
// SWZ: 0 = natural mapping (gx%8==0 pins B-col panels per XCD; single-batch GEMMs),
//      1 = bijective chunk (m204; one z-slice per XCD; z-batched attention GEMMs).
// LDS per buffer: A 256x64 f16 [0,32K), B [32K,64K); rows 128 B; granule(16B) swizzle g^=(row&7),
// stage writes linear (global_load_lds), inverse swizzle on the GLOBAL source col.
// OMODE: 0 = f32 out, 1 = f16 out, 2 = f16 exp(v*scale), 3 = f16 v*rcp(aux[z*2048+row]).
template <int OMODE, bool BIAS, bool SWZ>
__global__ __launch_bounds__(512, 2)
void gemm256(const _Float16* __restrict__ A, const _Float16* __restrict__ B,
             void* __restrict__ Cv, const float* __restrict__ aux, float scale,
             int K, int lda, int ldb, int ldc, int zmod,
             long a1, long a2, long b1, long b2, long c1, long c2) {
    __shared__ char lds[131072];
    int sbx, sby, sbz;
    if (SWZ) {
        const int gx = gridDim.x, gy = gridDim.y;
        const int nwg = gx * gy * gridDim.z;
        const int orig = (blockIdx.z * gy + blockIdx.y) * gx + blockIdx.x;
        const int q8 = nwg >> 3, r8 = nwg & 7;
        const int xcd = orig & 7, sub = orig >> 3;
        const int wgid = (xcd < r8 ? xcd * (q8 + 1) : r8 * (q8 + 1) + (xcd - r8) * q8) + sub;
        sbx = wgid % gx;
        const int tmp = wgid / gx;
        sby = tmp % gy; sbz = tmp / gy;
    } else {
        sbx = blockIdx.x; sby = blockIdx.y; sbz = blockIdx.z;
    }

    const int z = sbz, zq = z / zmod, zr = z - zq * zmod;
    A += zq * a1 + zr * a2;
    B += zq * b1 + zr * b2;
    const long coff = zq * c1 + zr * c2;
    const int tm = sby * 256, tn = sbx * 256;
    const int t = threadIdx.x;
    const int lane = t & 63, wid = t >> 6;
    const int wr = wid >> 2, wc = wid & 3;     // wave tile: rows wr*128, cols wc*64
    const int fr = lane & 15, kg = lane >> 4;

    // staging source (inverse-swizzled global col)
    const int strow = wid * 16 + (lane >> 3);
    const int stcol = ((lane & 7) ^ (lane >> 3)) * 8;
    const _Float16* gA = A + (long)(tm + strow) * lda + stcol;
    const _Float16* gB = B + (long)(tn + strow) * ldb + stcol;
    char* const ldsw = lds + wid * 2048;       // wave's linear chunk base (+1024 for 2nd load)

    // ds_read swizzled granule offsets (per lane, k-half h in {0,1})
    const int sw0 = 16 * ((0 * 4 + kg) ^ (fr & 7));
    const int sw1 = 16 * ((1 * 4 + kg) ^ (fr & 7));

    const int NT = K >> 6;
    f32x4 acc[8][4] = {};

    auto stageA = [&](int tt, int h) {
        const _Float16* s = gA + (long)(h * 128) * lda + tt * 64;
        char* d = ldsw + (tt & 1) * 65536 + h * 16384;
        gload_lds16(s, d);
        gload_lds16(s + (long)8 * lda, d + 1024);
    };
    auto stageB = [&](int tt, int h) {
        const _Float16* s = gB + (long)(h * 128) * ldb + tt * 64;
        char* d = ldsw + (tt & 1) * 65536 + 32768 + h * 16384;
        gload_lds16(s, d);
        gload_lds16(s + (long)8 * ldb, d + 1024);
    };

    // prologue: B(0), A(0) -> buf0; B(1) -> buf1; gate tile0 (vmcnt(4) leaves B(1) in flight)
    stageB(0, 0); stageB(0, 1); stageA(0, 0); stageA(0, 1);
    stageB(1, 0); stageB(1, 1);
    asm volatile("s_waitcnt vmcnt(4)" ::: "memory");
    barrier_fenced();

    f16x8 bf0[2][2], bf1[2][2];
    const int arow = (wr * 128 + fr) * 128;          // byte row base for A frags
    const int brow = 32768 + (wc * 64 + fr) * 128;   // byte row base for B frags

    for (int g = 0; g < NT; ++g) {
        const char* buf = lds + (g & 1) * 65536;
        // ---- half A: quadrants Q(0,0) + Q(0,1); stage A(g+1) into buf^1
        f16x8 af0[4][2];
#pragma unroll
        for (int m = 0; m < 4; ++m) {
            af0[m][0] = *(const f16x8*)(buf + arow + m * 2048 + sw0);
            af0[m][1] = *(const f16x8*)(buf + arow + m * 2048 + sw1);
        }
#pragma unroll
        for (int n = 0; n < 2; ++n) {
            bf0[n][0] = *(const f16x8*)(buf + brow + n * 2048 + sw0);
            bf0[n][1] = *(const f16x8*)(buf + brow + n * 2048 + sw1);
            bf1[n][0] = *(const f16x8*)(buf + brow + 4096 + n * 2048 + sw0);
            bf1[n][1] = *(const f16x8*)(buf + brow + 4096 + n * 2048 + sw1);
        }
        if (g + 1 < NT) { stageA(g + 1, 0); stageA(g + 1, 1); }
        __builtin_amdgcn_s_setprio(1);
#pragma unroll
        for (int m = 0; m < 4; ++m)
#pragma unroll
            for (int n = 0; n < 2; ++n)
#pragma unroll
                for (int k = 0; k < 2; ++k) {
                    acc[m][n]     = __builtin_amdgcn_mfma_f32_16x16x32_f16(af0[m][k], bf0[n][k], acc[m][n], 0, 0, 0);
                    acc[m][n + 2] = __builtin_amdgcn_mfma_f32_16x16x32_f16(af0[m][k], bf1[n][k], acc[m][n + 2], 0, 0, 0);
                }
        __builtin_amdgcn_s_setprio(0);
        barrier_fenced();   // closes all B reads: B(g+2) may now overwrite current B region
        // ---- half B: quadrants Q(1,1) + Q(1,0); stage B(g+2) into current buf
        f16x8 af1[4][2];
#pragma unroll
        for (int m = 0; m < 4; ++m) {
            af1[m][0] = *(const f16x8*)(buf + arow + 8192 + m * 2048 + sw0);
            af1[m][1] = *(const f16x8*)(buf + arow + 8192 + m * 2048 + sw1);
        }
        if (g + 2 < NT) { stageB(g + 2, 0); stageB(g + 2, 1); }
        __builtin_amdgcn_s_setprio(1);
#pragma unroll
        for (int m = 0; m < 4; ++m)
#pragma unroll
            for (int n = 0; n < 2; ++n)
#pragma unroll
                for (int k = 0; k < 2; ++k) {
                    acc[m + 4][n + 2] = __builtin_amdgcn_mfma_f32_16x16x32_f16(af1[m][k], bf1[n][k], acc[m + 4][n + 2], 0, 0, 0);
                    acc[m + 4][n]     = __builtin_amdgcn_mfma_f32_16x16x32_f16(af1[m][k], bf0[n][k], acc[m + 4][n], 0, 0, 0);
                }
        __builtin_amdgcn_s_setprio(0);
        // ---- gate for tile g+1 (counted; never drains mid-loop)
        if (g + 2 < NT)      asm volatile("s_waitcnt vmcnt(4)" ::: "memory");
        else if (g + 1 < NT) asm volatile("s_waitcnt vmcnt(0)" ::: "memory");
        barrier_fenced();   // also closes A(mg=1) reads before next tile's A(g+2) stage
    }

    // epilogue: C/D layout col = lane&15, row = (lane>>4)*4 + r
    const int rb = tm + wr * 128 + (lane >> 4) * 4;
    const int cb = tn + wc * 64 + fr;
    const float* auxz = (OMODE == 3) ? (aux + (long)z * 2048) : aux;
#pragma unroll
    for (int m = 0; m < 8; ++m) {
#pragma unroll
        for (int r = 0; r < 4; ++r) {
            const int row = rb + m * 16 + r;
            float inv = 1.0f;
            if (OMODE == 3) inv = __builtin_amdgcn_rcpf(auxz[row]);
#pragma unroll
            for (int n = 0; n < 4; ++n) {
                float v = acc[m][n][r];
                const int col = cb + n * 16;
                if (BIAS) v += aux[col];
                if (OMODE == 0) {
                    ((float*)Cv)[coff + (long)row * ldc + col] = v;
                } else {
                    if (OMODE == 2) v = __expf(v * scale);
                    if (OMODE == 3) v *= inv;
                    ((_Float16*)Cv)[coff + (long)row * ldc + col] = (_Float16)v;
                }
            }
        }
    }
}

extern "C" void kernel_launch(void* const* d_in, const int* in_sizes, int n_in,
                              void* d_out, int out_size, void* d_ws, size_t ws_size,
                              hipStream_t stream) {
    const float* x    = (const float*)d_in[0];   // (4,2048,2048)
    const float* wqkv = (const float*)d_in[1];   // (2048,6144)
    const float* wout = (const float*)d_in[2];   // (2048,2048)
    const float* bout = (const float*)d_in[3];   // (2048,)
    char* ws = (char*)d_ws;

    _Float16* qkv_h = (_Float16*)(ws);
    _Float16* x_h   = (_Float16*)(ws + 100663296);
    _Float16* wqkvT = (_Float16*)(ws + 134217728);
    _Float16* vT    = (_Float16*)(ws + 100663296);
    float*    cosT  = (float*)(ws + 100663296);   // alias: lives between QKV GEMM and v_transpose
    float*    sinT  = (float*)(ws + 104857600);
    _Float16* woutT = (_Float16*)(ws);
    const bool batched = ws_size >= 234946560ULL;  // incl. 64KB rowsum buffer

    // 1. x -> f16
    f32_to_f16_vec<<<dim3(16384), dim3(256), 0, stream>>>(x, x_h);
    // 2. wqkv (2048x6144) -> wqkvT (6144x2048) f16
    transpose_f32_to_f16<<<dim3(192, 64), dim3(256), 0, stream>>>(wqkv, wqkvT, 2048, 6144);
    // 3. qkv = x @ wqkv  (M=8192,N=6144,K=2048) -> f16  [natural order: XCD = bx%8 pins B cols]
    gemm256<1, false, false><<<dim3(24, 32, 1), dim3(512), 0, stream>>>(
        x_h, wqkvT, (void*)qkv_h, nullptr, 0.f, 2048, 2048, 2048, 6144,
        1, 0L, 0L, 0L, 0L, 0L, 0L);
    // 4. RoPE tables (x_h now dead; tables alias that region)
    rope_tables_k<<<dim3(4096), dim3(256), 0, stream>>>(cosT, sinT);
    // 5. RoPE in place on q,k halves (head-mixing rotation)
    rope_inplace<<<dim3(8192), dim3(256), 0, stream>>>(qkv_h, cosT, sinT);
    // 6. V transpose -> vT (b,h,d,s)  (overwrites table region; tables dead)
    v_transpose<<<dim3(64, 32, 8), dim3(256), 0, stream>>>(qkv_h, vT);

    if (batched) {
        _Float16* S16  = (_Float16*)(ws + 134217728);
        _Float16* aout = (_Float16*)(ws + 201326592);
        float*    lsum = (float*)(ws + 234881024);   // 8*2048 f32
        // 7. S~ = exp(scale * Q@K^T), all 8 (b,h)  [SWZ: one z-slice per XCD]
        gemm256<2, false, true><<<dim3(8, 8, 8), dim3(512), 0, stream>>>(
            qkv_h, qkv_h + 2048, (void*)S16, nullptr, 0.03125f, 1024, 6144, 6144, 2048,
            2, 12582912L, 1024L, 12582912L, 1024L, 8388608L, 4194304L);
        // 8. row sums of S~
        rowsum_f16<<<dim3(4096), dim3(256), 0, stream>>>(S16, lsum);
        // 9. O = (S~ @ V) / l  [SWZ: one z-slice per XCD]
        gemm256<3, false, true><<<dim3(4, 8, 8), dim3(512), 0, stream>>>(
            S16, vT, (void*)aout, lsum, 0.f, 2048, 2048, 2048, 2048,
            2, 8388608L, 4194304L, 4194304L, 2097152L, 4194304L, 1024L);
        // 10. wout -> woutT; out = aout @ wout + bout  [natural order]
        transpose_f32_to_f16<<<dim3(64, 64), dim3(256), 0, stream>>>(wout, woutT, 2048, 2048);
        gemm256<0, true, false><<<dim3(8, 32, 1), dim3(512), 0, stream>>>(
            aout, woutT, d_out, bout, 0.f, 2048, 2048, 2048, 2048,
            1, 0L, 0L, 0L, 0L, 0L, 0L);
    } else {
        float*    S32  = (float*)(ws + 134217728);
        _Float16* aout = (_Float16*)(ws + 150994944);
        for (int z = 0; z < 8; ++z) {
            const _Float16* Az = qkv_h + (long)(z >> 1) * 12582912 + (z & 1) * 1024;
            gemm256<0, false, false><<<dim3(8, 8, 1), dim3(512), 0, stream>>>(
                Az, Az + 2048, (void*)S32, nullptr, 0.f, 1024, 6144, 6144, 2048,
                1, 0L, 0L, 0L, 0L, 0L, 0L);
            softmax_rows_f32<<<dim3(512), dim3(256), 0, stream>>>(S32, 0.03125f);
            gemm256<1, false, false><<<dim3(4, 8, 1), dim3(512), 0, stream>>>(
                (const _Float16*)S32, vT + (long)z * 2097152,
                (void*)(aout + (long)(z >> 1) * 4194304 + (z & 1) * 1024), nullptr, 0.f,
                2048, 4096, 2048, 2048, 1, 0L, 0L, 0L, 0L, 0L, 0L);
        }
        transpose_f32_to_f16<<<dim3(64, 64), dim3(256), 0, stream>>>(wout, woutT, 2048, 2048);
        gemm256<0, true, false><<<dim3(8, 32, 1), dim3(512), 0, stream>>>(
            aout, woutT, d_out, bout, 0.f, 2048, 2048, 2048, 2048,
            1, 0L, 0L, 0L, 0L, 0L, 0L);
    }
}

// Round 21
// 480.348 us; speedup vs baseline: 1.0138x; 1.0105x over previous
//
#include <hip/hip_runtime.h>
#include <hip/hip_fp16.h>

typedef __attribute__((ext_vector_type(4))) float f32x4;
typedef __attribute__((ext_vector_type(8))) _Float16 f16x8;
typedef __attribute__((ext_vector_type(4))) _Float16 f16x4;

// ---------------- helpers ----------------
__device__ __forceinline__ void gload_lds16(const void* gp, void* lp) {
    __builtin_amdgcn_global_load_lds(
        (const __attribute__((address_space(1))) void*)gp,
        (__attribute__((address_space(3))) void*)lp, 16, 0, 0);
}

// Barrier as inline asm WITH memory clobber: raw __builtin_amdgcn_s_barrier() is
// IntrNoMem in LLVM, so LDS/global ops can be reordered across it (round-7 race).
__device__ __forceinline__ void barrier_fenced() {
    asm volatile("s_barrier" ::: "memory");
}

// ---------------- RoPE tables: cos/sin (2048 x 512) f32 ----------------
__global__ void rope_tables_k(float* __restrict__ cosT, float* __restrict__ sinT) {
    int idx = blockIdx.x * 256 + threadIdx.x;
    int s = idx >> 9, j = idx & 511;
    float invf = exp2f(-13.287712379549449f * (float)j * (1.0f / 512.0f)); // 10000^(-j/512)
    float ang = (float)s * invf;
    float sn, cs;
    sincosf(ang, &sn, &cs);
    cosT[idx] = cs;
    sinT[idx] = sn;
}

// ---------------- f32 -> f16 straight convert ----------------
__global__ void f32_to_f16_vec(const float* __restrict__ in, _Float16* __restrict__ out) {
    long i = ((long)blockIdx.x * 256 + threadIdx.x) * 4;
    f32x4 v = *(const f32x4*)(in + i);
    f16x4 h;
#pragma unroll
    for (int e = 0; e < 4; ++e) h[e] = (_Float16)v[e];
    *(f16x4*)(out + i) = h;
}

// ---------------- transpose + convert: in (R x C) f32 -> out (C x R) f16 ----------------
__global__ void transpose_f32_to_f16(const float* __restrict__ in, _Float16* __restrict__ out,
                                     int R, int C) {
    __shared__ _Float16 tile[32][36];
    const int c0 = blockIdx.x * 32, r0 = blockIdx.y * 32;
    const int t = threadIdx.x;
    const int r = t >> 3, c4 = (t & 7) * 4;
    f32x4 v = *(const f32x4*)(in + (long)(r0 + r) * C + c0 + c4);
    f16x4 h;
#pragma unroll
    for (int e = 0; e < 4; ++e) h[e] = (_Float16)v[e];
    *(f16x4*)&tile[r][c4] = h;
    __syncthreads();
    const int oc = t >> 3, o4 = (t & 7) * 4;
    f16x4 o;
#pragma unroll
    for (int e = 0; e < 4; ++e) o[e] = tile[o4 + e][oc];
    *(f16x4*)(out + (long)(c0 + oc) * R + r0 + o4) = o;
}

// ---------------- RoPE in-place on qkv rows (head-mixing: pair j with j+1024) ----------------
__global__ void rope_inplace(_Float16* __restrict__ qkv, const float* __restrict__ cosT,
                             const float* __restrict__ sinT) {
    const int row = blockIdx.x;            // b*2048 + s
    const int s = row & 2047;
    const int j0 = threadIdx.x * 4;        // [0,1024)
    _Float16* base = qkv + (long)row * 6144;
    f16x4 q0 = *(const f16x4*)(base + j0);
    f16x4 q1 = *(const f16x4*)(base + 1024 + j0);
    f16x4 k0 = *(const f16x4*)(base + 2048 + j0);
    f16x4 k1 = *(const f16x4*)(base + 3072 + j0);
    const int jj = j0 & 511;
    f32x4 cs = *(const f32x4*)(cosT + (long)s * 512 + jj);
    f32x4 sn = *(const f32x4*)(sinT + (long)s * 512 + jj);
    f16x4 oq0, oq1, ok0, ok1;
#pragma unroll
    for (int e = 0; e < 4; ++e) {
        float a = (float)q0[e], b = (float)q1[e];
        oq0[e] = (_Float16)(a * cs[e] - b * sn[e]);
        oq1[e] = (_Float16)(b * cs[e] + a * sn[e]);
        float c = (float)k0[e], d = (float)k1[e];
        ok0[e] = (_Float16)(c * cs[e] - d * sn[e]);
        ok1[e] = (_Float16)(d * cs[e] + c * sn[e]);
    }
    *(f16x4*)(base + j0) = oq0;
    *(f16x4*)(base + 1024 + j0) = oq1;
    *(f16x4*)(base + 2048 + j0) = ok0;
    *(f16x4*)(base + 3072 + j0) = ok1;
}

// ---------------- V transpose: qkv v-part (b,s,h,d) -> vT (b,h,d,s) f16 ----------------
__global__ void v_transpose(const _Float16* __restrict__ qkv, _Float16* __restrict__ vT) {
    __shared__ _Float16 tile[32][36];
    const int z = blockIdx.z, b = z >> 1, h = z & 1;
    const int s0 = blockIdx.x * 32, d0 = blockIdx.y * 32;
    const int t = threadIdx.x;
    const int r = t >> 3, c4 = (t & 7) * 4;
    const _Float16* src = qkv + (long)(b * 2048 + s0 + r) * 6144 + 4096 + h * 1024 + d0 + c4;
    *(f16x4*)&tile[r][c4] = *(const f16x4*)src;
    __syncthreads();
    const int dr = t >> 3, sc = (t & 7) * 4;
    f16x4 o;
#pragma unroll
    for (int e = 0; e < 4; ++e) o[e] = tile[sc + e][dr];
    *(f16x4*)(vT + ((long)z * 1024 + d0 + dr) * 2048 + s0 + sc) = o;
}

// ---------------- softmax on f32 rows (2048), writes f16 P in place (fallback path) ----------------
__global__ __launch_bounds__(256) void softmax_rows_f32(float* __restrict__ S, float scale) {
    const int wid = threadIdx.x >> 6, lane = threadIdx.x & 63;
    const long row = (long)blockIdx.x * 4 + wid;
    float* rp = S + row * 2048;
    f32x4 v[8];
    float mx = -1e30f;
#pragma unroll
    for (int i = 0; i < 8; ++i) {
        v[i] = *(const f32x4*)(rp + (i * 64 + lane) * 4);
#pragma unroll
        for (int e = 0; e < 4; ++e) mx = fmaxf(mx, v[i][e]);
    }
#pragma unroll
    for (int o = 32; o > 0; o >>= 1) mx = fmaxf(mx, __shfl_xor(mx, o, 64));
    float sum = 0.f;
#pragma unroll
    for (int i = 0; i < 8; ++i)
#pragma unroll
        for (int e = 0; e < 4; ++e) {
            float p = __expf(scale * (v[i][e] - mx));
            v[i][e] = p; sum += p;
        }
#pragma unroll
    for (int o = 32; o > 0; o >>= 1) sum += __shfl_xor(sum, o, 64);
    float inv = 1.0f / sum;
    _Float16* wp = (_Float16*)S + row * 4096;
#pragma unroll
    for (int i = 0; i < 8; ++i) {
        f16x4 h;
#pragma unroll
        for (int e = 0; e < 4; ++e) h[e] = (_Float16)(v[i][e] * inv);
        *(f16x4*)(wp + (i * 64 + lane) * 4) = h;
    }
}

// ---------------- fold 32 per-(block,wave) partials per row -> lsum (16384 rows) ----------------
__global__ __launch_bounds__(256) void rowsum32(const float* __restrict__ p,
                                                float* __restrict__ l) {
    const int i = blockIdx.x * 256 + threadIdx.x;   // 16384
    const float* q = p + (long)i * 32;
    float s = 0.f;
#pragma unroll
    for (int j = 0; j < 8; ++j) {
        f32x4 a = *(const f32x4*)(q + j * 4);
        s += (a[0] + a[1]) + (a[2] + a[3]);
    }
    l[i] = s;
}

// ---------------- GEMM 256x256, BK=64, 8 waves, 2-buffer LDS, 2-barrier/K-tile schedule ----------------
// BEST MEASURED STRUCTURE (round 15; rounds 16-18 variants all neutral/worse):
// per K-tile only the 2 load-bearing barriers:
//  (1) mid-tile (closes all B-fragment reads before B(g+2) overwrites current buf's B region),
//  (2) tile-end gate (counted vmcnt(4) + barrier; orders stages -> next tile's reads).
// vmcnt queue at gate: [A(g+1):4][B(g+2):4] -> vmcnt(4) retires A(g+1), leaves B(g+2).
// SWZ: 0 = natural mapping (gx%8==0 pins B-col panels per XCD; single-batch GEMMs),
//      1 = bijective chunk (m204; one z-slice per XCD; z-batched attention GEMMs).
// LDS per buffer: A 256x64 f16 [0,32K), B [32K,64K); rows 128 B; granule(16B) swizzle g^=(row&7),
// stage writes linear (global_load_lds), inverse swizzle on the GLOBAL source col.
// OMODE: 0 = f32 out (+bias), 1 = f16 out,
//        2 = f16 exp(v*scale) + DETERMINISTIC per-(block,wave) row-partials: fr-lane shfl
//            reduce, fr==0 stores aux[(z*2048+row)*32 + sbx*4 + wc]. ROUND-20 BUG FIX:
//            each row is covered by FOUR wc-waves (64 cols each); round 20 indexed by sbx
//            only -> 4-way write collision -> denominator ~4-32x small. wc now in the index;
//            every slot written exactly once (no atomics/memset; round-14 lesson).
//        3 = f16 v * rcp(aux[z*2048+row]).
template <int OMODE, bool BIAS, bool SWZ>
__global__ __launch_bounds__(512, 2)
void gemm256(const _Float16* __restrict__ A, const _Float16* __restrict__ B,
             void* __restrict__ Cv, const float* __restrict__ aux, float scale,
             int K, int lda, int ldb, int ldc, int zmod,
             long a1, long a2, long b1, long b2, long c1, long c2) {
    __shared__ char lds[131072];
    int sbx, sby, sbz;
    if (SWZ) {
        const int gx = gridDim.x, gy = gridDim.y;
        const int nwg = gx * gy * gridDim.z;
        const int orig = (blockIdx.z * gy + blockIdx.y) * gx + blockIdx.x;
        const int q8 = nwg >> 3, r8 = nwg & 7;
        const int xcd = orig & 7, sub = orig >> 3;
        const int wgid = (xcd < r8 ? xcd * (q8 + 1) : r8 * (q8 + 1) + (xcd - r8) * q8) + sub;
        sbx = wgid % gx;
        const int tmp = wgid / gx;
        sby = tmp % gy; sbz = tmp / gy;
    } else {
        sbx = blockIdx.x; sby = blockIdx.y; sbz = blockIdx.z;
    }

    const int z = sbz, zq = z / zmod, zr = z - zq * zmod;
    A += zq * a1 + zr * a2;
    B += zq * b1 + zr * b2;
    const long coff = zq * c1 + zr * c2;
    const int tm = sby * 256, tn = sbx * 256;
    const int t = threadIdx.x;
    const int lane = t & 63, wid = t >> 6;
    const int wr = wid >> 2, wc = wid & 3;     // wave tile: rows wr*128, cols wc*64
    const int fr = lane & 15, kg = lane >> 4;

    // staging source (inverse-swizzled global col)
    const int strow = wid * 16 + (lane >> 3);
    const int stcol = ((lane & 7) ^ (lane >> 3)) * 8;
    const _Float16* gA = A + (long)(tm + strow) * lda + stcol;
    const _Float16* gB = B + (long)(tn + strow) * ldb + stcol;
    char* const ldsw = lds + wid * 2048;       // wave's linear chunk base (+1024 for 2nd load)

    // ds_read swizzled granule offsets (per lane, k-half h in {0,1})
    const int sw0 = 16 * ((0 * 4 + kg) ^ (fr & 7));
    const int sw1 = 16 * ((1 * 4 + kg) ^ (fr & 7));

    const int NT = K >> 6;
    f32x4 acc[8][4] = {};

    auto stageA = [&](int tt, int h) {
        const _Float16* s = gA + (long)(h * 128) * lda + tt * 64;
        char* d = ldsw + (tt & 1) * 65536 + h * 16384;
        gload_lds16(s, d);
        gload_lds16(s + (long)8 * lda, d + 1024);
    };
    auto stageB = [&](int tt, int h) {
        const _Float16* s = gB + (long)(h * 128) * ldb + tt * 64;
        char* d = ldsw + (tt & 1) * 65536 + 32768 + h * 16384;
        gload_lds16(s, d);
        gload_lds16(s + (long)8 * ldb, d + 1024);
    };

    // prologue: B(0), A(0) -> buf0; B(1) -> buf1; gate tile0 (vmcnt(4) leaves B(1) in flight)
    stageB(0, 0); stageB(0, 1); stageA(0, 0); stageA(0, 1);
    stageB(1, 0); stageB(1, 1);
    asm volatile("s_waitcnt vmcnt(4)" ::: "memory");
    barrier_fenced();

    f16x8 bf0[2][2], bf1[2][2];
    const int arow = (wr * 128 + fr) * 128;          // byte row base for A frags
    const int brow = 32768 + (wc * 64 + fr) * 128;   // byte row base for B frags

    for (int g = 0; g < NT; ++g) {
        const char* buf = lds + (g & 1) * 65536;
        // ---- half A: quadrants Q(0,0) + Q(0,1); stage A(g+1) into buf^1
        f16x8 af0[4][2];
#pragma unroll
        for (int m = 0; m < 4; ++m) {
            af0[m][0] = *(const f16x8*)(buf + arow + m * 2048 + sw0);
            af0[m][1] = *(const f16x8*)(buf + arow + m * 2048 + sw1);
        }
#pragma unroll
        for (int n = 0; n < 2; ++n) {
            bf0[n][0] = *(const f16x8*)(buf + brow + n * 2048 + sw0);
            bf0[n][1] = *(const f16x8*)(buf + brow + n * 2048 + sw1);
            bf1[n][0] = *(const f16x8*)(buf + brow + 4096 + n * 2048 + sw0);
            bf1[n][1] = *(const f16x8*)(buf + brow + 4096 + n * 2048 + sw1);
        }
        if (g + 1 < NT) { stageA(g + 1, 0); stageA(g + 1, 1); }
        __builtin_amdgcn_s_setprio(1);
#pragma unroll
        for (int m = 0; m < 4; ++m)
#pragma unroll
            for (int n = 0; n < 2; ++n)
#pragma unroll
                for (int k = 0; k < 2; ++k) {
                    acc[m][n]     = __builtin_amdgcn_mfma_f32_16x16x32_f16(af0[m][k], bf0[n][k], acc[m][n], 0, 0, 0);
                    acc[m][n + 2] = __builtin_amdgcn_mfma_f32_16x16x32_f16(af0[m][k], bf1[n][k], acc[m][n + 2], 0, 0, 0);
                }
        __builtin_amdgcn_s_setprio(0);
        barrier_fenced();   // closes all B reads: B(g+2) may now overwrite current B region
        // ---- half B: quadrants Q(1,1) + Q(1,0); stage B(g+2) into current buf
        f16x8 af1[4][2];
#pragma unroll
        for (int m = 0; m < 4; ++m) {
            af1[m][0] = *(const f16x8*)(buf + arow + 8192 + m * 2048 + sw0);
            af1[m][1] = *(const f16x8*)(buf + arow + 8192 + m * 2048 + sw1);
        }
        if (g + 2 < NT) { stageB(g + 2, 0); stageB(g + 2, 1); }
        __builtin_amdgcn_s_setprio(1);
#pragma unroll
        for (int m = 0; m < 4; ++m)
#pragma unroll
            for (int n = 0; n < 2; ++n)
#pragma unroll
                for (int k = 0; k < 2; ++k) {
                    acc[m + 4][n + 2] = __builtin_amdgcn_mfma_f32_16x16x32_f16(af1[m][k], bf1[n][k], acc[m + 4][n + 2], 0, 0, 0);
                    acc[m + 4][n]     = __builtin_amdgcn_mfma_f32_16x16x32_f16(af1[m][k], bf0[n][k], acc[m + 4][n], 0, 0, 0);
                }
        __builtin_amdgcn_s_setprio(0);
        // ---- gate for tile g+1 (counted; never drains mid-loop)
        if (g + 2 < NT)      asm volatile("s_waitcnt vmcnt(4)" ::: "memory");
        else if (g + 1 < NT) asm volatile("s_waitcnt vmcnt(0)" ::: "memory");
        barrier_fenced();   // also closes A(mg=1) reads before next tile's A(g+2) stage
    }

    // epilogue: C/D layout col = lane&15, row = (lane>>4)*4 + r
    const int rb = tm + wr * 128 + (lane >> 4) * 4;
    const int cb = tn + wc * 64 + fr;
    const float* auxz = (OMODE == 3) ? (aux + (long)z * 2048) : aux;
#pragma unroll
    for (int m = 0; m < 8; ++m) {
#pragma unroll
        for (int r = 0; r < 4; ++r) {
            const int row = rb + m * 16 + r;
            float inv = 1.0f;
            if (OMODE == 3) inv = __builtin_amdgcn_rcpf(auxz[row]);
            float rsum = 0.f;
#pragma unroll
            for (int n = 0; n < 4; ++n) {
                float v = acc[m][n][r];
                const int col = cb + n * 16;
                if (BIAS) v += aux[col];
                if (OMODE == 0) {
                    ((float*)Cv)[coff + (long)row * ldc + col] = v;
                } else {
                    if (OMODE == 2) { v = __expf(v * scale); rsum += v; }
                    if (OMODE == 3) v *= inv;
                    ((_Float16*)Cv)[coff + (long)row * ldc + col] = (_Float16)v;
                }
            }
            if (OMODE == 2) {
                // reduce this row's 64-col slice over the 16 fr lanes (same kg group),
                // then ONE deterministic partial store per (row, block-col, wave-col)
#pragma unroll
                for (int o = 1; o < 16; o <<= 1) rsum += __shfl_xor(rsum, o, 64);
                if (fr == 0)
                    ((float*)aux)[(((long)z * 2048 + row) << 5) + sbx * 4 + wc] = rsum;
            }
        }
    }
}

extern "C" void kernel_launch(void* const* d_in, const int* in_sizes, int n_in,
                              void* d_out, int out_size, void* d_ws, size_t ws_size,
                              hipStream_t stream) {
    const float* x    = (const float*)d_in[0];   // (4,2048,2048)
    const float* wqkv = (const float*)d_in[1];   // (2048,6144)
    const float* wout = (const float*)d_in[2];   // (2048,2048)
    const float* bout = (const float*)d_in[3];   // (2048,)
    char* ws = (char*)d_ws;

    _Float16* qkv_h = (_Float16*)(ws);
    _Float16* x_h   = (_Float16*)(ws + 100663296);
    _Float16* wqkvT = (_Float16*)(ws + 134217728);
    _Float16* vT    = (_Float16*)(ws + 100663296);
    float*    cosT  = (float*)(ws + 100663296);   // alias: lives between QKV GEMM and v_transpose
    float*    sinT  = (float*)(ws + 104857600);
    _Float16* woutT = (_Float16*)(ws);
    const bool batched = ws_size >= 234946560ULL;  // incl. 64KB lsum buffer

    // 1. x -> f16
    f32_to_f16_vec<<<dim3(16384), dim3(256), 0, stream>>>(x, x_h);
    // 2. wqkv (2048x6144) -> wqkvT (6144x2048) f16
    transpose_f32_to_f16<<<dim3(192, 64), dim3(256), 0, stream>>>(wqkv, wqkvT, 2048, 6144);
    // 3. qkv = x @ wqkv  (M=8192,N=6144,K=2048) -> f16  [natural order: XCD = bx%8 pins B cols]
    gemm256<1, false, false><<<dim3(24, 32, 1), dim3(512), 0, stream>>>(
        x_h, wqkvT, (void*)qkv_h, nullptr, 0.f, 2048, 2048, 2048, 6144,
        1, 0L, 0L, 0L, 0L, 0L, 0L);
    // 4. RoPE tables (x_h now dead; tables alias that region)
    rope_tables_k<<<dim3(4096), dim3(256), 0, stream>>>(cosT, sinT);
    // 5. RoPE in place on q,k halves (head-mixing rotation)
    rope_inplace<<<dim3(8192), dim3(256), 0, stream>>>(qkv_h, cosT, sinT);
    // 6. V transpose -> vT (b,h,d,s)  (overwrites table region; tables dead)
    v_transpose<<<dim3(64, 32, 8), dim3(256), 0, stream>>>(qkv_h, vT);

    if (batched) {
        _Float16* S16  = (_Float16*)(ws + 134217728);
        float*    pp   = (float*)(ws + 201326592);   // 16384x32 f32 partials (2MB; aliases aout,
                                                     // fully consumed by rowsum32 before PV)
        _Float16* aout = (_Float16*)(ws + 201326592);
        float*    lsum = (float*)(ws + 234881024);   // 16384 f32
        // 7. S~ = exp(scale * Q@K^T) + per-(block,wave) row partials  [SWZ: z-slice per XCD]
        gemm256<2, false, true><<<dim3(8, 8, 8), dim3(512), 0, stream>>>(
            qkv_h, qkv_h + 2048, (void*)S16, pp, 0.03125f, 1024, 6144, 6144, 2048,
            2, 12582912L, 1024L, 12582912L, 1024L, 8388608L, 4194304L);
        // 8. fold 32 partials per row -> lsum (2MB L2-hot read; replaces 67MB S16 re-read)
        rowsum32<<<dim3(64), dim3(256), 0, stream>>>(pp, lsum);
        // 9. O = (S~ @ V) / l  [SWZ: one z-slice per XCD; aout overwrites consumed pp]
        gemm256<3, false, true><<<dim3(4, 8, 8), dim3(512), 0, stream>>>(
            S16, vT, (void*)aout, lsum, 0.f, 2048, 2048, 2048, 2048,
            2, 8388608L, 4194304L, 4194304L, 2097152L, 4194304L, 1024L);
        // 10. wout -> woutT; out = aout @ wout + bout  [natural order]
        transpose_f32_to_f16<<<dim3(64, 64), dim3(256), 0, stream>>>(wout, woutT, 2048, 2048);
        gemm256<0, true, false><<<dim3(8, 32, 1), dim3(512), 0, stream>>>(
            aout, woutT, d_out, bout, 0.f, 2048, 2048, 2048, 2048,
            1, 0L, 0L, 0L, 0L, 0L, 0L);
    } else {
        float*    S32  = (float*)(ws + 134217728);
        _Float16* aout = (_Float16*)(ws + 150994944);
        for (int z = 0; z < 8; ++z) {
            const _Float16* Az = qkv_h + (long)(z >> 1) * 12582912 + (z & 1) * 1024;
            gemm256<0, false, false><<<dim3(8, 8, 1), dim3(512), 0, stream>>>(
                Az, Az + 2048, (void*)S32, nullptr, 0.f, 1024, 6144, 6144, 2048,
                1, 0L, 0L, 0L, 0L, 0L, 0L);
            softmax_rows_f32<<<dim3(512), dim3(256), 0, stream>>>(S32, 0.03125f);
            gemm256<1, false, false><<<dim3(4, 8, 1), dim3(512), 0, stream>>>(
                (const _Float16*)S32, vT + (long)z * 2097152,
                (void*)(aout + (long)(z >> 1) * 4194304 + (z & 1) * 1024), nullptr, 0.f,
                2048, 4096, 2048, 2048, 1, 0L, 0L, 0L, 0L, 0L, 0L);
        }
        transpose_f32_to_f16<<<dim3(64, 64), dim3(256), 0, stream>>>(wout, woutT, 2048, 2048);
        gemm256<0, true, false><<<dim3(8, 32, 1), dim3(512), 0, stream>>>(
            aout, woutT, d_out, bout, 0.f, 2048, 2048, 2048, 2048,
            1, 0L, 0L, 0L, 0L, 0L, 0L);
    }
}

// Round 22
// 479.804 us; speedup vs baseline: 1.0150x; 1.0011x over previous
//
#include <hip/hip_runtime.h>
#include <hip/hip_fp16.h>

typedef __attribute__((ext_vector_type(4))) float f32x4;
typedef __attribute__((ext_vector_type(8))) _Float16 f16x8;
typedef __attribute__((ext_vector_type(4))) _Float16 f16x4;

// ---------------- helpers ----------------
__device__ __forceinline__ void gload_lds16(const void* gp, void* lp) {
    __builtin_amdgcn_global_load_lds(
        (const __attribute__((address_space(1))) void*)gp,
        (__attribute__((address_space(3))) void*)lp, 16, 0, 0);
}

// Barrier as inline asm WITH memory clobber: raw __builtin_amdgcn_s_barrier() is
// IntrNoMem in LLVM, so LDS/global ops can be reordered across it (round-7 race).
__device__ __forceinline__ void barrier_fenced() {
    asm volatile("s_barrier" ::: "memory");
}

// ---------------- RoPE tables: cos/sin (2048 x 512) f32 ----------------
__global__ void rope_tables_k(float* __restrict__ cosT, float* __restrict__ sinT) {
    int idx = blockIdx.x * 256 + threadIdx.x;
    int s = idx >> 9, j = idx & 511;
    float invf = exp2f(-13.287712379549449f * (float)j * (1.0f / 512.0f)); // 10000^(-j/512)
    float ang = (float)s * invf;
    float sn, cs;
    sincosf(ang, &sn, &cs);
    cosT[idx] = cs;
    sinT[idx] = sn;
}

// ---------------- f32 -> f16 straight convert (8 elems/thread: 32B load, 16B store) ----------------
__global__ void f32_to_f16_vec(const float* __restrict__ in, _Float16* __restrict__ out) {
    long i = ((long)blockIdx.x * 256 + threadIdx.x) * 8;
    f32x4 v0 = *(const f32x4*)(in + i);
    f32x4 v1 = *(const f32x4*)(in + i + 4);
    f16x8 h;
#pragma unroll
    for (int e = 0; e < 4; ++e) { h[e] = (_Float16)v0[e]; h[e + 4] = (_Float16)v1[e]; }
    *(f16x8*)(out + i) = h;
}

// ---------------- transpose + convert: in (R x C) f32 -> out (C x R) f16 ----------------
__global__ void transpose_f32_to_f16(const float* __restrict__ in, _Float16* __restrict__ out,
                                     int R, int C) {
    __shared__ _Float16 tile[32][36];
    const int c0 = blockIdx.x * 32, r0 = blockIdx.y * 32;
    const int t = threadIdx.x;
    const int r = t >> 3, c4 = (t & 7) * 4;
    f32x4 v = *(const f32x4*)(in + (long)(r0 + r) * C + c0 + c4);
    f16x4 h;
#pragma unroll
    for (int e = 0; e < 4; ++e) h[e] = (_Float16)v[e];
    *(f16x4*)&tile[r][c4] = h;
    __syncthreads();
    const int oc = t >> 3, o4 = (t & 7) * 4;
    f16x4 o;
#pragma unroll
    for (int e = 0; e < 4; ++e) o[e] = tile[o4 + e][oc];
    *(f16x4*)(out + (long)(c0 + oc) * R + r0 + o4) = o;
}

// ---------------- RoPE in-place, 8 elems/thread (head-mixing: pair j with j+1024) ----------------
// grid 4096 x 256: 2 rows/block, 128 threads/row, j0 = (t&127)*8
__global__ void rope_inplace(_Float16* __restrict__ qkv, const float* __restrict__ cosT,
                             const float* __restrict__ sinT) {
    const int t = threadIdx.x;
    const int row = blockIdx.x * 2 + (t >> 7);   // b*2048 + s
    const int s = row & 2047;
    const int j0 = (t & 127) * 8;                // [0,1024)
    _Float16* base = qkv + (long)row * 6144;
    f16x8 q0 = *(const f16x8*)(base + j0);
    f16x8 q1 = *(const f16x8*)(base + 1024 + j0);
    f16x8 k0 = *(const f16x8*)(base + 2048 + j0);
    f16x8 k1 = *(const f16x8*)(base + 3072 + j0);
    const int jj = j0 & 511;
    f32x4 cs0 = *(const f32x4*)(cosT + (long)s * 512 + jj);
    f32x4 cs1 = *(const f32x4*)(cosT + (long)s * 512 + jj + 4);
    f32x4 sn0 = *(const f32x4*)(sinT + (long)s * 512 + jj);
    f32x4 sn1 = *(const f32x4*)(sinT + (long)s * 512 + jj + 4);
    f16x8 oq0, oq1, ok0, ok1;
#pragma unroll
    for (int e = 0; e < 8; ++e) {
        const float cs = (e < 4) ? cs0[e & 3] : cs1[e & 3];
        const float sn = (e < 4) ? sn0[e & 3] : sn1[e & 3];
        float a = (float)q0[e], b = (float)q1[e];
        oq0[e] = (_Float16)(a * cs - b * sn);
        oq1[e] = (_Float16)(b * cs + a * sn);
        float c = (float)k0[e], d = (float)k1[e];
        ok0[e] = (_Float16)(c * cs - d * sn);
        ok1[e] = (_Float16)(d * cs + c * sn);
    }
    *(f16x8*)(base + j0) = oq0;
    *(f16x8*)(base + 1024 + j0) = oq1;
    *(f16x8*)(base + 2048 + j0) = ok0;
    *(f16x8*)(base + 3072 + j0) = ok1;
}

// ---------------- V transpose: qkv v-part (b,s,h,d) -> vT (b,h,d,s) f16 ----------------
__global__ void v_transpose(const _Float16* __restrict__ qkv, _Float16* __restrict__ vT) {
    __shared__ _Float16 tile[32][36];
    const int z = blockIdx.z, b = z >> 1, h = z & 1;
    const int s0 = blockIdx.x * 32, d0 = blockIdx.y * 32;
    const int t = threadIdx.x;
    const int r = t >> 3, c4 = (t & 7) * 4;
    const _Float16* src = qkv + (long)(b * 2048 + s0 + r) * 6144 + 4096 + h * 1024 + d0 + c4;
    *(f16x4*)&tile[r][c4] = *(const f16x4*)src;
    __syncthreads();
    const int dr = t >> 3, sc = (t & 7) * 4;
    f16x4 o;
#pragma unroll
    for (int e = 0; e < 4; ++e) o[e] = tile[sc + e][dr];
    *(f16x4*)(vT + ((long)z * 1024 + d0 + dr) * 2048 + s0 + sc) = o;
}

// ---------------- softmax on f32 rows (2048), writes f16 P in place (fallback path) ----------------
__global__ __launch_bounds__(256) void softmax_rows_f32(float* __restrict__ S, float scale) {
    const int wid = threadIdx.x >> 6, lane = threadIdx.x & 63;
    const long row = (long)blockIdx.x * 4 + wid;
    float* rp = S + row * 2048;
    f32x4 v[8];
    float mx = -1e30f;
#pragma unroll
    for (int i = 0; i < 8; ++i) {
        v[i] = *(const f32x4*)(rp + (i * 64 + lane) * 4);
#pragma unroll
        for (int e = 0; e < 4; ++e) mx = fmaxf(mx, v[i][e]);
    }
#pragma unroll
    for (int o = 32; o > 0; o >>= 1) mx = fmaxf(mx, __shfl_xor(mx, o, 64));
    float sum = 0.f;
#pragma unroll
    for (int i = 0; i < 8; ++i)
#pragma unroll
        for (int e = 0; e < 4; ++e) {
            float p = __expf(scale * (v[i][e] - mx));
            v[i][e] = p; sum += p;
        }
#pragma unroll
    for (int o = 32; o > 0; o >>= 1) sum += __shfl_xor(sum, o, 64);
    float inv = 1.0f / sum;
    _Float16* wp = (_Float16*)S + row * 4096;
#pragma unroll
    for (int i = 0; i < 8; ++i) {
        f16x4 h;
#pragma unroll
        for (int e = 0; e < 4; ++e) h[e] = (_Float16)(v[i][e] * inv);
        *(f16x4*)(wp + (i * 64 + lane) * 4) = h;
    }
}

// ---------------- fold 32 per-(block,wave) partials per row -> lsum (16384 rows) ----------------
__global__ __launch_bounds__(256) void rowsum32(const float* __restrict__ p,
                                                float* __restrict__ l) {
    const int i = blockIdx.x * 256 + threadIdx.x;   // 16384
    const float* q = p + (long)i * 32;
    float s = 0.f;
#pragma unroll
    for (int j = 0; j < 8; ++j) {
        f32x4 a = *(const f32x4*)(q + j * 4);
        s += (a[0] + a[1]) + (a[2] + a[3]);
    }
    l[i] = s;
}

// ---------------- GEMM 256x256, BK=64, 8 waves, 2-buffer LDS, 2-barrier/K-tile schedule ----------------
// BEST MEASURED STRUCTURE (round 15/21): per K-tile only the 2 load-bearing barriers:
//  (1) mid-tile (closes all B-fragment reads before B(g+2) overwrites current buf's B region),
//  (2) tile-end gate (counted vmcnt(4) + barrier; orders stages -> next tile's reads).
// vmcnt queue at gate: [A(g+1):4][B(g+2):4] -> vmcnt(4) retires A(g+1), leaves B(g+2).
// SWZ: 0 = natural mapping (gx%8==0 pins B-col panels per XCD; single-batch GEMMs),
//      1 = bijective chunk (m204; one z-slice per XCD; z-batched attention GEMMs).
// LDS per buffer: A 256x64 f16 [0,32K), B [32K,64K); rows 128 B; granule(16B) swizzle g^=(row&7),
// stage writes linear (global_load_lds), inverse swizzle on the GLOBAL source col.
// OMODE: 0 = f32 out (+bias), 1 = f16 out,
//        2 = f16 exp(v*scale) + DETERMINISTIC per-(block,wave) row-partials: fr-lane shfl
//            reduce, fr==0 stores aux[(z*2048+row)*32 + sbx*4 + wc] (round-21 verified),
//        3 = f16 v * rcp(aux[z*2048+row]).
template <int OMODE, bool BIAS, bool SWZ>
__global__ __launch_bounds__(512, 2)
void gemm256(const _Float16* __restrict__ A, const _Float16* __restrict__ B,
             void* __restrict__ Cv, const float* __restrict__ aux, float scale,
             int K, int lda, int ldb, int ldc, int zmod,
             long a1, long a2, long b1, long b2, long c1, long c2) {
    __shared__ char lds[131072];
    int sbx, sby, sbz;
    if (SWZ) {
        const int gx = gridDim.x, gy = gridDim.y;
        const int nwg = gx * gy * gridDim.z;
        const int orig = (blockIdx.z * gy + blockIdx.y) * gx + blockIdx.x;
        const int q8 = nwg >> 3, r8 = nwg & 7;
        const int xcd = orig & 7, sub = orig >> 3;
        const int wgid = (xcd < r8 ? xcd * (q8 + 1) : r8 * (q8 + 1) + (xcd - r8) * q8) + sub;
        sbx = wgid % gx;
        const int tmp = wgid / gx;
        sby = tmp % gy; sbz = tmp / gy;
    } else {
        sbx = blockIdx.x; sby = blockIdx.y; sbz = blockIdx.z;
    }

    const int z = sbz, zq = z / zmod, zr = z - zq * zmod;
    A += zq * a1 + zr * a2;
    B += zq * b1 + zr * b2;
    const long coff = zq * c1 + zr * c2;
    const int tm = sby * 256, tn = sbx * 256;
    const int t = threadIdx.x;
    const int lane = t & 63, wid = t >> 6;
    const int wr = wid >> 2, wc = wid & 3;     // wave tile: rows wr*128, cols wc*64
    const int fr = lane & 15, kg = lane >> 4;

    // staging source (inverse-swizzled global col)
    const int strow = wid * 16 + (lane >> 3);
    const int stcol = ((lane & 7) ^ (lane >> 3)) * 8;
    const _Float16* gA = A + (long)(tm + strow) * lda + stcol;
    const _Float16* gB = B + (long)(tn + strow) * ldb + stcol;
    char* const ldsw = lds + wid * 2048;       // wave's linear chunk base (+1024 for 2nd load)

    // ds_read swizzled granule offsets (per lane, k-half h in {0,1})
    const int sw0 = 16 * ((0 * 4 + kg) ^ (fr & 7));
    const int sw1 = 16 * ((1 * 4 + kg) ^ (fr & 7));

    const int NT = K >> 6;
    f32x4 acc[8][4] = {};

    auto stageA = [&](int tt, int h) {
        const _Float16* s = gA + (long)(h * 128) * lda + tt * 64;
        char* d = ldsw + (tt & 1) * 65536 + h * 16384;
        gload_lds16(s, d);
        gload_lds16(s + (long)8 * lda, d + 1024);
    };
    auto stageB = [&](int tt, int h) {
        const _Float16* s = gB + (long)(h * 128) * ldb + tt * 64;
        char* d = ldsw + (tt & 1) * 65536 + 32768 + h * 16384;
        gload_lds16(s, d);
        gload_lds16(s + (long)8 * ldb, d + 1024);
    };

    // prologue: B(0), A(0) -> buf0; B(1) -> buf1; gate tile0 (vmcnt(4) leaves B(1) in flight)
    stageB(0, 0); stageB(0, 1); stageA(0, 0); stageA(0, 1);
    stageB(1, 0); stageB(1, 1);
    asm volatile("s_waitcnt vmcnt(4)" ::: "memory");
    barrier_fenced();

    f16x8 bf0[2][2], bf1[2][2];
    const int arow = (wr * 128 + fr) * 128;          // byte row base for A frags
    const int brow = 32768 + (wc * 64 + fr) * 128;   // byte row base for B frags

    for (int g = 0; g < NT; ++g) {
        const char* buf = lds + (g & 1) * 65536;
        // ---- half A: quadrants Q(0,0) + Q(0,1); stage A(g+1) into buf^1
        f16x8 af0[4][2];
#pragma unroll
        for (int m = 0; m < 4; ++m) {
            af0[m][0] = *(const f16x8*)(buf + arow + m * 2048 + sw0);
            af0[m][1] = *(const f16x8*)(buf + arow + m * 2048 + sw1);
        }
#pragma unroll
        for (int n = 0; n < 2; ++n) {
            bf0[n][0] = *(const f16x8*)(buf + brow + n * 2048 + sw0);
            bf0[n][1] = *(const f16x8*)(buf + brow + n * 2048 + sw1);
            bf1[n][0] = *(const f16x8*)(buf + brow + 4096 + n * 2048 + sw0);
            bf1[n][1] = *(const f16x8*)(buf + brow + 4096 + n * 2048 + sw1);
        }
        if (g + 1 < NT) { stageA(g + 1, 0); stageA(g + 1, 1); }
        __builtin_amdgcn_s_setprio(1);
#pragma unroll
        for (int m = 0; m < 4; ++m)
#pragma unroll
            for (int n = 0; n < 2; ++n)
#pragma unroll
                for (int k = 0; k < 2; ++k) {
                    acc[m][n]     = __builtin_amdgcn_mfma_f32_16x16x32_f16(af0[m][k], bf0[n][k], acc[m][n], 0, 0, 0);
                    acc[m][n + 2] = __builtin_amdgcn_mfma_f32_16x16x32_f16(af0[m][k], bf1[n][k], acc[m][n + 2], 0, 0, 0);
                }
        __builtin_amdgcn_s_setprio(0);
        barrier_fenced();   // closes all B reads: B(g+2) may now overwrite current B region
        // ---- half B: quadrants Q(1,1) + Q(1,0); stage B(g+2) into current buf
        f16x8 af1[4][2];
#pragma unroll
        for (int m = 0; m < 4; ++m) {
            af1[m][0] = *(const f16x8*)(buf + arow + 8192 + m * 2048 + sw0);
            af1[m][1] = *(const f16x8*)(buf + arow + 8192 + m * 2048 + sw1);
        }
        if (g + 2 < NT) { stageB(g + 2, 0); stageB(g + 2, 1); }
        __builtin_amdgcn_s_setprio(1);
#pragma unroll
        for (int m = 0; m < 4; ++m)
#pragma unroll
            for (int n = 0; n < 2; ++n)
#pragma unroll
                for (int k = 0; k < 2; ++k) {
                    acc[m + 4][n + 2] = __builtin_amdgcn_mfma_f32_16x16x32_f16(af1[m][k], bf1[n][k], acc[m + 4][n + 2], 0, 0, 0);
                    acc[m + 4][n]     = __builtin_amdgcn_mfma_f32_16x16x32_f16(af1[m][k], bf0[n][k], acc[m + 4][n], 0, 0, 0);
                }
        __builtin_amdgcn_s_setprio(0);
        // ---- gate for tile g+1 (counted; never drains mid-loop)
        if (g + 2 < NT)      asm volatile("s_waitcnt vmcnt(4)" ::: "memory");
        else if (g + 1 < NT) asm volatile("s_waitcnt vmcnt(0)" ::: "memory");
        barrier_fenced();   // also closes A(mg=1) reads before next tile's A(g+2) stage
    }

    // epilogue: C/D layout col = lane&15, row = (lane>>4)*4 + r
    const int rb = tm + wr * 128 + (lane >> 4) * 4;
    const int cb = tn + wc * 64 + fr;
    const float* auxz = (OMODE == 3) ? (aux + (long)z * 2048) : aux;
#pragma unroll
    for (int m = 0; m < 8; ++m) {
#pragma unroll
        for (int r = 0; r < 4; ++r) {
            const int row = rb + m * 16 + r;
            float inv = 1.0f;
            if (OMODE == 3) inv = __builtin_amdgcn_rcpf(auxz[row]);
            float rsum = 0.f;
#pragma unroll
            for (int n = 0; n < 4; ++n) {
                float v = acc[m][n][r];
                const int col = cb + n * 16;
                if (BIAS) v += aux[col];
                if (OMODE == 0) {
                    ((float*)Cv)[coff + (long)row * ldc + col] = v;
                } else {
                    if (OMODE == 2) { v = __expf(v * scale); rsum += v; }
                    if (OMODE == 3) v *= inv;
                    ((_Float16*)Cv)[coff + (long)row * ldc + col] = (_Float16)v;
                }
            }
            if (OMODE == 2) {
#pragma unroll
                for (int o = 1; o < 16; o <<= 1) rsum += __shfl_xor(rsum, o, 64);
                if (fr == 0)
                    ((float*)aux)[(((long)z * 2048 + row) << 5) + sbx * 4 + wc] = rsum;
            }
        }
    }
}

extern "C" void kernel_launch(void* const* d_in, const int* in_sizes, int n_in,
                              void* d_out, int out_size, void* d_ws, size_t ws_size,
                              hipStream_t stream) {
    const float* x    = (const float*)d_in[0];   // (4,2048,2048)
    const float* wqkv = (const float*)d_in[1];   // (2048,6144)
    const float* wout = (const float*)d_in[2];   // (2048,2048)
    const float* bout = (const float*)d_in[3];   // (2048,)
    char* ws = (char*)d_ws;

    _Float16* qkv_h = (_Float16*)(ws);
    _Float16* x_h   = (_Float16*)(ws + 100663296);
    _Float16* wqkvT = (_Float16*)(ws + 134217728);
    _Float16* vT    = (_Float16*)(ws + 100663296);
    float*    cosT  = (float*)(ws + 100663296);   // alias: lives between QKV GEMM and v_transpose
    float*    sinT  = (float*)(ws + 104857600);
    _Float16* woutT = (_Float16*)(ws);
    const bool batched = ws_size >= 234946560ULL;  // incl. 64KB lsum buffer

    // 1. x -> f16 (8 elems/thread)
    f32_to_f16_vec<<<dim3(8192), dim3(256), 0, stream>>>(x, x_h);
    // 2. wqkv (2048x6144) -> wqkvT (6144x2048) f16
    transpose_f32_to_f16<<<dim3(192, 64), dim3(256), 0, stream>>>(wqkv, wqkvT, 2048, 6144);
    // 3. qkv = x @ wqkv  (M=8192,N=6144,K=2048) -> f16  [natural order: XCD = bx%8 pins B cols]
    gemm256<1, false, false><<<dim3(24, 32, 1), dim3(512), 0, stream>>>(
        x_h, wqkvT, (void*)qkv_h, nullptr, 0.f, 2048, 2048, 2048, 6144,
        1, 0L, 0L, 0L, 0L, 0L, 0L);
    // 4. RoPE tables (x_h now dead; tables alias that region)
    rope_tables_k<<<dim3(4096), dim3(256), 0, stream>>>(cosT, sinT);
    // 5. RoPE in place on q,k halves (head-mixing rotation; 8 elems/thread, 2 rows/block)
    rope_inplace<<<dim3(4096), dim3(256), 0, stream>>>(qkv_h, cosT, sinT);
    // 6. V transpose -> vT (b,h,d,s)  (overwrites table region; tables dead)
    v_transpose<<<dim3(64, 32, 8), dim3(256), 0, stream>>>(qkv_h, vT);

    if (batched) {
        _Float16* S16  = (_Float16*)(ws + 134217728);
        float*    pp   = (float*)(ws + 201326592);   // 16384x32 f32 partials (2MB; aliases aout,
                                                     // fully consumed by rowsum32 before PV)
        _Float16* aout = (_Float16*)(ws + 201326592);
        float*    lsum = (float*)(ws + 234881024);   // 16384 f32
        // 7. S~ = exp(scale * Q@K^T) + per-(block,wave) row partials  [SWZ: z-slice per XCD]
        gemm256<2, false, true><<<dim3(8, 8, 8), dim3(512), 0, stream>>>(
            qkv_h, qkv_h + 2048, (void*)S16, pp, 0.03125f, 1024, 6144, 6144, 2048,
            2, 12582912L, 1024L, 12582912L, 1024L, 8388608L, 4194304L);
        // 8. fold 32 partials per row -> lsum (2MB L2-hot read; replaces 67MB S16 re-read)
        rowsum32<<<dim3(64), dim3(256), 0, stream>>>(pp, lsum);
        // 9. O = (S~ @ V) / l  [SWZ: one z-slice per XCD; aout overwrites consumed pp]
        gemm256<3, false, true><<<dim3(4, 8, 8), dim3(512), 0, stream>>>(
            S16, vT, (void*)aout, lsum, 0.f, 2048, 2048, 2048, 2048,
            2, 8388608L, 4194304L, 4194304L, 2097152L, 4194304L, 1024L);
        // 10. wout -> woutT; out = aout @ wout + bout  [natural order]
        transpose_f32_to_f16<<<dim3(64, 64), dim3(256), 0, stream>>>(wout, woutT, 2048, 2048);
        gemm256<0, true, false><<<dim3(8, 32, 1), dim3(512), 0, stream>>>(
            aout, woutT, d_out, bout, 0.f, 2048, 2048, 2048, 2048,
            1, 0L, 0L, 0L, 0L, 0L, 0L);
    } else {
        float*    S32  = (float*)(ws + 134217728);
        _Float16* aout = (_Float16*)(ws + 150994944);
        for (int z = 0; z < 8; ++z) {
            const _Float16* Az = qkv_h + (long)(z >> 1) * 12582912 + (z & 1) * 1024;
            gemm256<0, false, false><<<dim3(8, 8, 1), dim3(512), 0, stream>>>(
                Az, Az + 2048, (void*)S32, nullptr, 0.f, 1024, 6144, 6144, 2048,
                1, 0L, 0L, 0L, 0L, 0L, 0L);
            softmax_rows_f32<<<dim3(512), dim3(256), 0, stream>>>(S32, 0.03125f);
            gemm256<1, false, false><<<dim3(4, 8, 1), dim3(512), 0, stream>>>(
                (const _Float16*)S32, vT + (long)z * 2097152,
                (void*)(aout + (long)(z >> 1) * 4194304 + (z & 1) * 1024), nullptr, 0.f,
                2048, 4096, 2048, 2048, 1, 0L, 0L, 0L, 0L, 0L, 0L);
        }
        transpose_f32_to_f16<<<dim3(64, 64), dim3(256), 0, stream>>>(wout, woutT, 2048, 2048);
        gemm256<0, true, false><<<dim3(8, 32, 1), dim3(512), 0, stream>>>(
            aout, woutT, d_out, bout, 0.f, 2048, 2048, 2048, 2048,
            1, 0L, 0L, 0L, 0L, 0L, 0L);
    }
}

// Round 23
// 470.906 us; speedup vs baseline: 1.0341x; 1.0189x over previous
//
#include <hip/hip_runtime.h>
#include <hip/hip_fp16.h>

typedef __attribute__((ext_vector_type(4))) float f32x4;
typedef __attribute__((ext_vector_type(8))) _Float16 f16x8;
typedef __attribute__((ext_vector_type(4))) _Float16 f16x4;

// ---------------- helpers ----------------
__device__ __forceinline__ void gload_lds16(const void* gp, void* lp) {
    __builtin_amdgcn_global_load_lds(
        (const __attribute__((address_space(1))) void*)gp,
        (__attribute__((address_space(3))) void*)lp, 16, 0, 0);
}

// Barrier as inline asm WITH memory clobber: raw __builtin_amdgcn_s_barrier() is
// IntrNoMem in LLVM, so LDS/global ops can be reordered across it (round-7 race).
__device__ __forceinline__ void barrier_fenced() {
    asm volatile("s_barrier" ::: "memory");
}

// ---------------- RoPE tables: cos/sin (2048 x 512) f32 ----------------
__global__ void rope_tables_k(float* __restrict__ cosT, float* __restrict__ sinT) {
    int idx = blockIdx.x * 256 + threadIdx.x;
    int s = idx >> 9, j = idx & 511;
    float invf = exp2f(-13.287712379549449f * (float)j * (1.0f / 512.0f)); // 10000^(-j/512)
    float ang = (float)s * invf;
    float sn, cs;
    sincosf(ang, &sn, &cs);
    cosT[idx] = cs;
    sinT[idx] = sn;
}

// ---------------- f32 -> f16 straight convert (8 elems/thread) ----------------
__global__ void f32_to_f16_vec(const float* __restrict__ in, _Float16* __restrict__ out) {
    long i = ((long)blockIdx.x * 256 + threadIdx.x) * 8;
    f32x4 v0 = *(const f32x4*)(in + i);
    f32x4 v1 = *(const f32x4*)(in + i + 4);
    f16x8 h;
#pragma unroll
    for (int e = 0; e < 4; ++e) { h[e] = (_Float16)v0[e]; h[e + 4] = (_Float16)v1[e]; }
    *(f16x8*)(out + i) = h;
}

// ---------------- transpose + convert: in (R x C) f32 -> out (C x R) f16 ----------------
__global__ void transpose_f32_to_f16(const float* __restrict__ in, _Float16* __restrict__ out,
                                     int R, int C) {
    __shared__ _Float16 tile[32][36];
    const int c0 = blockIdx.x * 32, r0 = blockIdx.y * 32;
    const int t = threadIdx.x;
    const int r = t >> 3, c4 = (t & 7) * 4;
    f32x4 v = *(const f32x4*)(in + (long)(r0 + r) * C + c0 + c4);
    f16x4 h;
#pragma unroll
    for (int e = 0; e < 4; ++e) h[e] = (_Float16)v[e];
    *(f16x4*)&tile[r][c4] = h;
    __syncthreads();
    const int oc = t >> 3, o4 = (t & 7) * 4;
    f16x4 o;
#pragma unroll
    for (int e = 0; e < 4; ++e) o[e] = tile[o4 + e][oc];
    *(f16x4*)(out + (long)(c0 + oc) * R + r0 + o4) = o;
}

// ---------------- MERGED pre-pass: x->f16 | wqkv transpose | RoPE tables ----------------
// blocks [0,8192): x convert; [8192,20480): wqkv (2048x6144) -> wqkvT; [20480,24576): tables.
// Branch is block-uniform (syncthreads inside the transpose branch is legal).
__global__ __launch_bounds__(256) void pre_pass(const float* __restrict__ x,
                                                _Float16* __restrict__ x_h,
                                                const float* __restrict__ wqkv,
                                                _Float16* __restrict__ wqkvT,
                                                float* __restrict__ cosT,
                                                float* __restrict__ sinT) {
    __shared__ _Float16 tile[32][36];
    const int bid = blockIdx.x;
    const int t = threadIdx.x;
    if (bid < 8192) {
        long i = ((long)bid * 256 + t) * 8;
        f32x4 v0 = *(const f32x4*)(x + i);
        f32x4 v1 = *(const f32x4*)(x + i + 4);
        f16x8 h;
#pragma unroll
        for (int e = 0; e < 4; ++e) { h[e] = (_Float16)v0[e]; h[e + 4] = (_Float16)v1[e]; }
        *(f16x8*)(x_h + i) = h;
    } else if (bid < 20480) {
        const int b2 = bid - 8192;                 // 12288 = 192 x 64
        const int c0 = (b2 % 192) * 32, r0 = (b2 / 192) * 32;   // C=6144, R=2048
        const int r = t >> 3, c4 = (t & 7) * 4;
        f32x4 v = *(const f32x4*)(wqkv + (long)(r0 + r) * 6144 + c0 + c4);
        f16x4 h;
#pragma unroll
        for (int e = 0; e < 4; ++e) h[e] = (_Float16)v[e];
        *(f16x4*)&tile[r][c4] = h;
        __syncthreads();
        const int oc = t >> 3, o4 = (t & 7) * 4;
        f16x4 o;
#pragma unroll
        for (int e = 0; e < 4; ++e) o[e] = tile[o4 + e][oc];
        *(f16x4*)(wqkvT + (long)(c0 + oc) * 2048 + r0 + o4) = o;
    } else {
        const int idx = (bid - 20480) * 256 + t;   // 2048*512
        const int s = idx >> 9, j = idx & 511;
        float invf = exp2f(-13.287712379549449f * (float)j * (1.0f / 512.0f));
        float ang = (float)s * invf;
        float sn, cs;
        sincosf(ang, &sn, &cs);
        cosT[idx] = cs;
        sinT[idx] = sn;
    }
}

// ---------------- RoPE in-place, 8 elems/thread (head-mixing: pair j with j+1024) ----------------
__global__ void rope_inplace(_Float16* __restrict__ qkv, const float* __restrict__ cosT,
                             const float* __restrict__ sinT) {
    const int t = threadIdx.x;
    const int row = blockIdx.x * 2 + (t >> 7);   // b*2048 + s
    const int s = row & 2047;
    const int j0 = (t & 127) * 8;                // [0,1024)
    _Float16* base = qkv + (long)row * 6144;
    f16x8 q0 = *(const f16x8*)(base + j0);
    f16x8 q1 = *(const f16x8*)(base + 1024 + j0);
    f16x8 k0 = *(const f16x8*)(base + 2048 + j0);
    f16x8 k1 = *(const f16x8*)(base + 3072 + j0);
    const int jj = j0 & 511;
    f32x4 cs0 = *(const f32x4*)(cosT + (long)s * 512 + jj);
    f32x4 cs1 = *(const f32x4*)(cosT + (long)s * 512 + jj + 4);
    f32x4 sn0 = *(const f32x4*)(sinT + (long)s * 512 + jj);
    f32x4 sn1 = *(const f32x4*)(sinT + (long)s * 512 + jj + 4);
    f16x8 oq0, oq1, ok0, ok1;
#pragma unroll
    for (int e = 0; e < 8; ++e) {
        const float cs = (e < 4) ? cs0[e & 3] : cs1[e & 3];
        const float sn = (e < 4) ? sn0[e & 3] : sn1[e & 3];
        float a = (float)q0[e], b = (float)q1[e];
        oq0[e] = (_Float16)(a * cs - b * sn);
        oq1[e] = (_Float16)(b * cs + a * sn);
        float c = (float)k0[e], d = (float)k1[e];
        ok0[e] = (_Float16)(c * cs - d * sn);
        ok1[e] = (_Float16)(d * cs + c * sn);
    }
    *(f16x8*)(base + j0) = oq0;
    *(f16x8*)(base + 1024 + j0) = oq1;
    *(f16x8*)(base + 2048 + j0) = ok0;
    *(f16x8*)(base + 3072 + j0) = ok1;
}

// ---------------- V transpose: qkv v-part (b,s,h,d) -> vT (b,h,d,s) f16 ----------------
__global__ void v_transpose(const _Float16* __restrict__ qkv, _Float16* __restrict__ vT) {
    __shared__ _Float16 tile[32][36];
    const int z = blockIdx.z, b = z >> 1, h = z & 1;
    const int s0 = blockIdx.x * 32, d0 = blockIdx.y * 32;
    const int t = threadIdx.x;
    const int r = t >> 3, c4 = (t & 7) * 4;
    const _Float16* src = qkv + (long)(b * 2048 + s0 + r) * 6144 + 4096 + h * 1024 + d0 + c4;
    *(f16x4*)&tile[r][c4] = *(const f16x4*)src;
    __syncthreads();
    const int dr = t >> 3, sc = (t & 7) * 4;
    f16x4 o;
#pragma unroll
    for (int e = 0; e < 4; ++e) o[e] = tile[sc + e][dr];
    *(f16x4*)(vT + ((long)z * 1024 + d0 + dr) * 2048 + s0 + sc) = o;
}

// ---------------- MERGED: RoPE (q,k) | V transpose (disjoint regions of qkv) ----------------
// blocks [0,4096): rope 2 rows/block; [4096,20480): v-transpose flattened (64 x 32 x 8).
__global__ __launch_bounds__(256) void rope_vt(_Float16* __restrict__ qkv,
                                               const float* __restrict__ cosT,
                                               const float* __restrict__ sinT,
                                               _Float16* __restrict__ vT) {
    __shared__ _Float16 tile[32][36];
    const int bid = blockIdx.x;
    const int t = threadIdx.x;
    if (bid < 4096) {
        const int row = bid * 2 + (t >> 7);
        const int s = row & 2047;
        const int j0 = (t & 127) * 8;
        _Float16* base = qkv + (long)row * 6144;
        f16x8 q0 = *(const f16x8*)(base + j0);
        f16x8 q1 = *(const f16x8*)(base + 1024 + j0);
        f16x8 k0 = *(const f16x8*)(base + 2048 + j0);
        f16x8 k1 = *(const f16x8*)(base + 3072 + j0);
        const int jj = j0 & 511;
        f32x4 cs0 = *(const f32x4*)(cosT + (long)s * 512 + jj);
        f32x4 cs1 = *(const f32x4*)(cosT + (long)s * 512 + jj + 4);
        f32x4 sn0 = *(const f32x4*)(sinT + (long)s * 512 + jj);
        f32x4 sn1 = *(const f32x4*)(sinT + (long)s * 512 + jj + 4);
        f16x8 oq0, oq1, ok0, ok1;
#pragma unroll
        for (int e = 0; e < 8; ++e) {
            const float cs = (e < 4) ? cs0[e & 3] : cs1[e & 3];
            const float sn = (e < 4) ? sn0[e & 3] : sn1[e & 3];
            float a = (float)q0[e], b = (float)q1[e];
            oq0[e] = (_Float16)(a * cs - b * sn);
            oq1[e] = (_Float16)(b * cs + a * sn);
            float c = (float)k0[e], d = (float)k1[e];
            ok0[e] = (_Float16)(c * cs - d * sn);
            ok1[e] = (_Float16)(d * cs + c * sn);
        }
        *(f16x8*)(base + j0) = oq0;
        *(f16x8*)(base + 1024 + j0) = oq1;
        *(f16x8*)(base + 2048 + j0) = ok0;
        *(f16x8*)(base + 3072 + j0) = ok1;
    } else {
        const int vid = bid - 4096;                // 16384 = 64 x 32 x 8
        const int z = vid >> 11, rem = vid & 2047;
        const int s0 = (rem & 63) * 32, d0 = (rem >> 6) * 32;
        const int b = z >> 1, h = z & 1;
        const int r = t >> 3, c4 = (t & 7) * 4;
        const _Float16* src = qkv + (long)(b * 2048 + s0 + r) * 6144 + 4096 + h * 1024 + d0 + c4;
        *(f16x4*)&tile[r][c4] = *(const f16x4*)src;
        __syncthreads();
        const int dr = t >> 3, sc = (t & 7) * 4;
        f16x4 o;
#pragma unroll
        for (int e = 0; e < 4; ++e) o[e] = tile[sc + e][dr];
        *(f16x4*)(vT + ((long)z * 1024 + d0 + dr) * 2048 + s0 + sc) = o;
    }
}

// ---------------- softmax on f32 rows (2048), writes f16 P in place (fallback path) ----------------
__global__ __launch_bounds__(256) void softmax_rows_f32(float* __restrict__ S, float scale) {
    const int wid = threadIdx.x >> 6, lane = threadIdx.x & 63;
    const long row = (long)blockIdx.x * 4 + wid;
    float* rp = S + row * 2048;
    f32x4 v[8];
    float mx = -1e30f;
#pragma unroll
    for (int i = 0; i < 8; ++i) {
        v[i] = *(const f32x4*)(rp + (i * 64 + lane) * 4);
#pragma unroll
        for (int e = 0; e < 4; ++e) mx = fmaxf(mx, v[i][e]);
    }
#pragma unroll
    for (int o = 32; o > 0; o >>= 1) mx = fmaxf(mx, __shfl_xor(mx, o, 64));
    float sum = 0.f;
#pragma unroll
    for (int i = 0; i < 8; ++i)
#pragma unroll
        for (int e = 0; e < 4; ++e) {
            float p = __expf(scale * (v[i][e] - mx));
            v[i][e] = p; sum += p;
        }
#pragma unroll
    for (int o = 32; o > 0; o >>= 1) sum += __shfl_xor(sum, o, 64);
    float inv = 1.0f / sum;
    _Float16* wp = (_Float16*)S + row * 4096;
#pragma unroll
    for (int i = 0; i < 8; ++i) {
        f16x4 h;
#pragma unroll
        for (int e = 0; e < 4; ++e) h[e] = (_Float16)(v[i][e] * inv);
        *(f16x4*)(wp + (i * 64 + lane) * 4) = h;
    }
}

// ---------------- fold 32 per-(block,wave) partials per row -> lsum (16384 rows) ----------------
__global__ __launch_bounds__(256) void rowsum32(const float* __restrict__ p,
                                                float* __restrict__ l) {
    const int i = blockIdx.x * 256 + threadIdx.x;   // 16384
    const float* q = p + (long)i * 32;
    float s = 0.f;
#pragma unroll
    for (int j = 0; j < 8; ++j) {
        f32x4 a = *(const f32x4*)(q + j * 4);
        s += (a[0] + a[1]) + (a[2] + a[3]);
    }
    l[i] = s;
}

// ---------------- GEMM 256x256, BK=64, 8 waves, 2-buffer LDS, 2-barrier/K-tile schedule ----------------
// BEST MEASURED STRUCTURE (round 15/21/22): per K-tile only the 2 load-bearing barriers:
//  (1) mid-tile (closes all B-fragment reads before B(g+2) overwrites current buf's B region),
//  (2) tile-end gate (counted vmcnt(4) + barrier; orders stages -> next tile's reads).
// vmcnt queue at gate: [A(g+1):4][B(g+2):4] -> vmcnt(4) retires A(g+1), leaves B(g+2).
// SWZ: 0 = natural mapping (gx%8==0 pins B-col panels per XCD; single-batch GEMMs),
//      1 = bijective chunk (m204; one z-slice per XCD; z-batched attention GEMMs).
// LDS per buffer: A 256x64 f16 [0,32K), B [32K,64K); rows 128 B; granule(16B) swizzle g^=(row&7),
// stage writes linear (global_load_lds), inverse swizzle on the GLOBAL source col.
// OMODE: 0 = f32 out (+bias), 1 = f16 out,
//        2 = f16 exp(v*scale) + DETERMINISTIC per-(block,wave) row-partials: fr-lane shfl
//            reduce, fr==0 stores aux[(z*2048+row)*32 + sbx*4 + wc] (round-21 verified),
//        3 = f16 v * rcp(aux[z*2048+row]).
template <int OMODE, bool BIAS, bool SWZ>
__global__ __launch_bounds__(512, 2)
void gemm256(const _Float16* __restrict__ A, const _Float16* __restrict__ B,
             void* __restrict__ Cv, const float* __restrict__ aux, float scale,
             int K, int lda, int ldb, int ldc, int zmod,
             long a1, long a2, long b1, long b2, long c1, long c2) {
    __shared__ char lds[131072];
    int sbx, sby, sbz;
    if (SWZ) {
        const int gx = gridDim.x, gy = gridDim.y;
        const int nwg = gx * gy * gridDim.z;
        const int orig = (blockIdx.z * gy + blockIdx.y) * gx + blockIdx.x;
        const int q8 = nwg >> 3, r8 = nwg & 7;
        const int xcd = orig & 7, sub = orig >> 3;
        const int wgid = (xcd < r8 ? xcd * (q8 + 1) : r8 * (q8 + 1) + (xcd - r8) * q8) + sub;
        sbx = wgid % gx;
        const int tmp = wgid / gx;
        sby = tmp % gy; sbz = tmp / gy;
    } else {
        sbx = blockIdx.x; sby = blockIdx.y; sbz = blockIdx.z;
    }

    const int z = sbz, zq = z / zmod, zr = z - zq * zmod;
    A += zq * a1 + zr * a2;
    B += zq * b1 + zr * b2;
    const long coff = zq * c1 + zr * c2;
    const int tm = sby * 256, tn = sbx * 256;
    const int t = threadIdx.x;
    const int lane = t & 63, wid = t >> 6;
    const int wr = wid >> 2, wc = wid & 3;     // wave tile: rows wr*128, cols wc*64
    const int fr = lane & 15, kg = lane >> 4;

    // staging source (inverse-swizzled global col)
    const int strow = wid * 16 + (lane >> 3);
    const int stcol = ((lane & 7) ^ (lane >> 3)) * 8;
    const _Float16* gA = A + (long)(tm + strow) * lda + stcol;
    const _Float16* gB = B + (long)(tn + strow) * ldb + stcol;
    char* const ldsw = lds + wid * 2048;       // wave's linear chunk base (+1024 for 2nd load)

    // ds_read swizzled granule offsets (per lane, k-half h in {0,1})
    const int sw0 = 16 * ((0 * 4 + kg) ^ (fr & 7));
    const int sw1 = 16 * ((1 * 4 + kg) ^ (fr & 7));

    const int NT = K >> 6;
    f32x4 acc[8][4] = {};

    auto stageA = [&](int tt, int h) {
        const _Float16* s = gA + (long)(h * 128) * lda + tt * 64;
        char* d = ldsw + (tt & 1) * 65536 + h * 16384;
        gload_lds16(s, d);
        gload_lds16(s + (long)8 * lda, d + 1024);
    };
    auto stageB = [&](int tt, int h) {
        const _Float16* s = gB + (long)(h * 128) * ldb + tt * 64;
        char* d = ldsw + (tt & 1) * 65536 + 32768 + h * 16384;
        gload_lds16(s, d);
        gload_lds16(s + (long)8 * ldb, d + 1024);
    };

    // prologue: B(0), A(0) -> buf0; B(1) -> buf1; gate tile0 (vmcnt(4) leaves B(1) in flight)
    stageB(0, 0); stageB(0, 1); stageA(0, 0); stageA(0, 1);
    stageB(1, 0); stageB(1, 1);
    asm volatile("s_waitcnt vmcnt(4)" ::: "memory");
    barrier_fenced();

    f16x8 bf0[2][2], bf1[2][2];
    const int arow = (wr * 128 + fr) * 128;          // byte row base for A frags
    const int brow = 32768 + (wc * 64 + fr) * 128;   // byte row base for B frags

    for (int g = 0; g < NT; ++g) {
        const char* buf = lds + (g & 1) * 65536;
        // ---- half A: quadrants Q(0,0) + Q(0,1); stage A(g+1) into buf^1
        f16x8 af0[4][2];
#pragma unroll
        for (int m = 0; m < 4; ++m) {
            af0[m][0] = *(const f16x8*)(buf + arow + m * 2048 + sw0);
            af0[m][1] = *(const f16x8*)(buf + arow + m * 2048 + sw1);
        }
#pragma unroll
        for (int n = 0; n < 2; ++n) {
            bf0[n][0] = *(const f16x8*)(buf + brow + n * 2048 + sw0);
            bf0[n][1] = *(const f16x8*)(buf + brow + n * 2048 + sw1);
            bf1[n][0] = *(const f16x8*)(buf + brow + 4096 + n * 2048 + sw0);
            bf1[n][1] = *(const f16x8*)(buf + brow + 4096 + n * 2048 + sw1);
        }
        if (g + 1 < NT) { stageA(g + 1, 0); stageA(g + 1, 1); }
        __builtin_amdgcn_s_setprio(1);
#pragma unroll
        for (int m = 0; m < 4; ++m)
#pragma unroll
            for (int n = 0; n < 2; ++n)
#pragma unroll
                for (int k = 0; k < 2; ++k) {
                    acc[m][n]     = __builtin_amdgcn_mfma_f32_16x16x32_f16(af0[m][k], bf0[n][k], acc[m][n], 0, 0, 0);
                    acc[m][n + 2] = __builtin_amdgcn_mfma_f32_16x16x32_f16(af0[m][k], bf1[n][k], acc[m][n + 2], 0, 0, 0);
                }
        __builtin_amdgcn_s_setprio(0);
        barrier_fenced();   // closes all B reads: B(g+2) may now overwrite current B region
        // ---- half B: quadrants Q(1,1) + Q(1,0); stage B(g+2) into current buf
        f16x8 af1[4][2];
#pragma unroll
        for (int m = 0; m < 4; ++m) {
            af1[m][0] = *(const f16x8*)(buf + arow + 8192 + m * 2048 + sw0);
            af1[m][1] = *(const f16x8*)(buf + arow + 8192 + m * 2048 + sw1);
        }
        if (g + 2 < NT) { stageB(g + 2, 0); stageB(g + 2, 1); }
        __builtin_amdgcn_s_setprio(1);
#pragma unroll
        for (int m = 0; m < 4; ++m)
#pragma unroll
            for (int n = 0; n < 2; ++n)
#pragma unroll
                for (int k = 0; k < 2; ++k) {
                    acc[m + 4][n + 2] = __builtin_amdgcn_mfma_f32_16x16x32_f16(af1[m][k], bf1[n][k], acc[m + 4][n + 2], 0, 0, 0);
                    acc[m + 4][n]     = __builtin_amdgcn_mfma_f32_16x16x32_f16(af1[m][k], bf0[n][k], acc[m + 4][n], 0, 0, 0);
                }
        __builtin_amdgcn_s_setprio(0);
        // ---- gate for tile g+1 (counted; never drains mid-loop)
        if (g + 2 < NT)      asm volatile("s_waitcnt vmcnt(4)" ::: "memory");
        else if (g + 1 < NT) asm volatile("s_waitcnt vmcnt(0)" ::: "memory");
        barrier_fenced();   // also closes A(mg=1) reads before next tile's A(g+2) stage
    }

    // epilogue: C/D layout col = lane&15, row = (lane>>4)*4 + r
    const int rb = tm + wr * 128 + (lane >> 4) * 4;
    const int cb = tn + wc * 64 + fr;
    const float* auxz = (OMODE == 3) ? (aux + (long)z * 2048) : aux;
#pragma unroll
    for (int m = 0; m < 8; ++m) {
#pragma unroll
        for (int r = 0; r < 4; ++r) {
            const int row = rb + m * 16 + r;
            float inv = 1.0f;
            if (OMODE == 3) inv = __builtin_amdgcn_rcpf(auxz[row]);
            float rsum = 0.f;
#pragma unroll
            for (int n = 0; n < 4; ++n) {
                float v = acc[m][n][r];
                const int col = cb + n * 16;
                if (BIAS) v += aux[col];
                if (OMODE == 0) {
                    ((float*)Cv)[coff + (long)row * ldc + col] = v;
                } else {
                    if (OMODE == 2) { v = __expf(v * scale); rsum += v; }
                    if (OMODE == 3) v *= inv;
                    ((_Float16*)Cv)[coff + (long)row * ldc + col] = (_Float16)v;
                }
            }
            if (OMODE == 2) {
#pragma unroll
                for (int o = 1; o < 16; o <<= 1) rsum += __shfl_xor(rsum, o, 64);
                if (fr == 0)
                    ((float*)aux)[(((long)z * 2048 + row) << 5) + sbx * 4 + wc] = rsum;
            }
        }
    }
}

extern "C" void kernel_launch(void* const* d_in, const int* in_sizes, int n_in,
                              void* d_out, int out_size, void* d_ws, size_t ws_size,
                              hipStream_t stream) {
    const float* x    = (const float*)d_in[0];   // (4,2048,2048)
    const float* wqkv = (const float*)d_in[1];   // (2048,6144)
    const float* wout = (const float*)d_in[2];   // (2048,2048)
    const float* bout = (const float*)d_in[3];   // (2048,)
    char* ws = (char*)d_ws;

    _Float16* qkv_h = (_Float16*)(ws);
    _Float16* x_h   = (_Float16*)(ws + 100663296);
    _Float16* wqkvT = (_Float16*)(ws + 134217728);
    _Float16* vT    = (_Float16*)(ws + 100663296);
    _Float16* woutT = (_Float16*)(ws);
    const bool batched = ws_size >= 234946560ULL;  // incl. 64KB lsum buffer

    if (batched) {
        // tables live in the gap after wqkvT, inside the future-S16 region; they are
        // consumed by rope_vt BEFORE QK overwrites the region with S16.
        float*    cosT = (float*)(ws + 159383552);
        float*    sinT = (float*)(ws + 163577856);
        _Float16* S16  = (_Float16*)(ws + 134217728);
        float*    pp   = (float*)(ws + 201326592);   // 16384x32 f32 partials (2MB; aliases aout,
                                                     // fully consumed by rowsum32 before PV)
        _Float16* aout = (_Float16*)(ws + 201326592);
        float*    lsum = (float*)(ws + 234881024);   // 16384 f32
        // 1. merged pre-pass: x->f16 | wqkvT | RoPE tables
        pre_pass<<<dim3(24576), dim3(256), 0, stream>>>(x, x_h, wqkv, wqkvT, cosT, sinT);
        // 2. qkv = x @ wqkv  [natural order: XCD = bx%8 pins B cols]
        gemm256<1, false, false><<<dim3(24, 32, 1), dim3(512), 0, stream>>>(
            x_h, wqkvT, (void*)qkv_h, nullptr, 0.f, 2048, 2048, 2048, 6144,
            1, 0L, 0L, 0L, 0L, 0L, 0L);
        // 3. merged RoPE (q,k in place) | V transpose -> vT
        rope_vt<<<dim3(20480), dim3(256), 0, stream>>>(qkv_h, cosT, sinT, vT);
        // 4. S~ = exp(scale * Q@K^T) + per-(block,wave) row partials  [SWZ: z-slice per XCD]
        gemm256<2, false, true><<<dim3(8, 8, 8), dim3(512), 0, stream>>>(
            qkv_h, qkv_h + 2048, (void*)S16, pp, 0.03125f, 1024, 6144, 6144, 2048,
            2, 12582912L, 1024L, 12582912L, 1024L, 8388608L, 4194304L);
        // 5. fold 32 partials per row -> lsum
        rowsum32<<<dim3(64), dim3(256), 0, stream>>>(pp, lsum);
        // 6. O = (S~ @ V) / l  [SWZ; aout overwrites consumed pp]
        gemm256<3, false, true><<<dim3(4, 8, 8), dim3(512), 0, stream>>>(
            S16, vT, (void*)aout, lsum, 0.f, 2048, 2048, 2048, 2048,
            2, 8388608L, 4194304L, 4194304L, 2097152L, 4194304L, 1024L);
        // 7. wout -> woutT; out = aout @ wout + bout  [natural order]
        transpose_f32_to_f16<<<dim3(64, 64), dim3(256), 0, stream>>>(wout, woutT, 2048, 2048);
        gemm256<0, true, false><<<dim3(8, 32, 1), dim3(512), 0, stream>>>(
            aout, woutT, d_out, bout, 0.f, 2048, 2048, 2048, 2048,
            1, 0L, 0L, 0L, 0L, 0L, 0L);
    } else {
        float*    cosT = (float*)(ws + 100663296);
        float*    sinT = (float*)(ws + 104857600);
        float*    S32  = (float*)(ws + 134217728);
        _Float16* aout = (_Float16*)(ws + 150994944);
        f32_to_f16_vec<<<dim3(8192), dim3(256), 0, stream>>>(x, x_h);
        transpose_f32_to_f16<<<dim3(192, 64), dim3(256), 0, stream>>>(wqkv, wqkvT, 2048, 6144);
        gemm256<1, false, false><<<dim3(24, 32, 1), dim3(512), 0, stream>>>(
            x_h, wqkvT, (void*)qkv_h, nullptr, 0.f, 2048, 2048, 2048, 6144,
            1, 0L, 0L, 0L, 0L, 0L, 0L);
        rope_tables_k<<<dim3(4096), dim3(256), 0, stream>>>(cosT, sinT);
        rope_inplace<<<dim3(4096), dim3(256), 0, stream>>>(qkv_h, cosT, sinT);
        v_transpose<<<dim3(64, 32, 8), dim3(256), 0, stream>>>(qkv_h, vT);
        for (int z = 0; z < 8; ++z) {
            const _Float16* Az = qkv_h + (long)(z >> 1) * 12582912 + (z & 1) * 1024;
            gemm256<0, false, false><<<dim3(8, 8, 1), dim3(512), 0, stream>>>(
                Az, Az + 2048, (void*)S32, nullptr, 0.f, 1024, 6144, 6144, 2048,
                1, 0L, 0L, 0L, 0L, 0L, 0L);
            softmax_rows_f32<<<dim3(512), dim3(256), 0, stream>>>(S32, 0.03125f);
            gemm256<1, false, false><<<dim3(4, 8, 1), dim3(512), 0, stream>>>(
                (const _Float16*)S32, vT + (long)z * 2097152,
                (void*)(aout + (long)(z >> 1) * 4194304 + (z & 1) * 1024), nullptr, 0.f,
                2048, 4096, 2048, 2048, 1, 0L, 0L, 0L, 0L, 0L, 0L);
        }
        transpose_f32_to_f16<<<dim3(64, 64), dim3(256), 0, stream>>>(wout, woutT, 2048, 2048);
        gemm256<0, true, false><<<dim3(8, 32, 1), dim3(512), 0, stream>>>(
            aout, woutT, d_out, bout, 0.f, 2048, 2048, 2048, 2048,
            1, 0L, 0L, 0L, 0L, 0L, 0L);
    }
}

// Round 24
// 468.831 us; speedup vs baseline: 1.0387x; 1.0044x over previous
//
#include <hip/hip_runtime.h>
#include <hip/hip_fp16.h>

typedef __attribute__((ext_vector_type(4))) float f32x4;
typedef __attribute__((ext_vector_type(8))) _Float16 f16x8;
typedef __attribute__((ext_vector_type(4))) _Float16 f16x4;

// ---------------- helpers ----------------
__device__ __forceinline__ void gload_lds16(const void* gp, void* lp) {
    __builtin_amdgcn_global_load_lds(
        (const __attribute__((address_space(1))) void*)gp,
        (__attribute__((address_space(3))) void*)lp, 16, 0, 0);
}

// Barrier as inline asm WITH memory clobber: raw __builtin_amdgcn_s_barrier() is
// IntrNoMem in LLVM, so LDS/global ops can be reordered across it (round-7 race).
__device__ __forceinline__ void barrier_fenced() {
    asm volatile("s_barrier" ::: "memory");
}

// ---------------- RoPE tables: cos/sin (2048 x 512) f32 (fallback path) ----------------
__global__ void rope_tables_k(float* __restrict__ cosT, float* __restrict__ sinT) {
    int idx = blockIdx.x * 256 + threadIdx.x;
    int s = idx >> 9, j = idx & 511;
    float invf = exp2f(-13.287712379549449f * (float)j * (1.0f / 512.0f)); // 10000^(-j/512)
    float ang = (float)s * invf;
    float sn, cs;
    sincosf(ang, &sn, &cs);
    cosT[idx] = cs;
    sinT[idx] = sn;
}

// ---------------- f32 -> f16 straight convert (8 elems/thread) ----------------
__global__ void f32_to_f16_vec(const float* __restrict__ in, _Float16* __restrict__ out) {
    long i = ((long)blockIdx.x * 256 + threadIdx.x) * 8;
    f32x4 v0 = *(const f32x4*)(in + i);
    f32x4 v1 = *(const f32x4*)(in + i + 4);
    f16x8 h;
#pragma unroll
    for (int e = 0; e < 4; ++e) { h[e] = (_Float16)v0[e]; h[e + 4] = (_Float16)v1[e]; }
    *(f16x8*)(out + i) = h;
}

// ---------------- transpose + convert: in (R x C) f32 -> out (C x R) f16 ----------------
__global__ void transpose_f32_to_f16(const float* __restrict__ in, _Float16* __restrict__ out,
                                     int R, int C) {
    __shared__ _Float16 tile[32][36];
    const int c0 = blockIdx.x * 32, r0 = blockIdx.y * 32;
    const int t = threadIdx.x;
    const int r = t >> 3, c4 = (t & 7) * 4;
    f32x4 v = *(const f32x4*)(in + (long)(r0 + r) * C + c0 + c4);
    f16x4 h;
#pragma unroll
    for (int e = 0; e < 4; ++e) h[e] = (_Float16)v[e];
    *(f16x4*)&tile[r][c4] = h;
    __syncthreads();
    const int oc = t >> 3, o4 = (t & 7) * 4;
    f16x4 o;
#pragma unroll
    for (int e = 0; e < 4; ++e) o[e] = tile[o4 + e][oc];
    *(f16x4*)(out + (long)(c0 + oc) * R + r0 + o4) = o;
}

// ---------------- MERGED pre-pass: x->f16 | wqkv transpose | RoPE tables ----------------
// blocks [0,8192): x convert; [8192,20480): wqkv (2048x6144) -> wqkvT; [20480,24576): tables.
// Branch is block-uniform (syncthreads inside the transpose branch is legal).
__global__ __launch_bounds__(256) void pre_pass(const float* __restrict__ x,
                                                _Float16* __restrict__ x_h,
                                                const float* __restrict__ wqkv,
                                                _Float16* __restrict__ wqkvT,
                                                float* __restrict__ cosT,
                                                float* __restrict__ sinT) {
    __shared__ _Float16 tile[32][36];
    const int bid = blockIdx.x;
    const int t = threadIdx.x;
    if (bid < 8192) {
        long i = ((long)bid * 256 + t) * 8;
        f32x4 v0 = *(const f32x4*)(x + i);
        f32x4 v1 = *(const f32x4*)(x + i + 4);
        f16x8 h;
#pragma unroll
        for (int e = 0; e < 4; ++e) { h[e] = (_Float16)v0[e]; h[e + 4] = (_Float16)v1[e]; }
        *(f16x8*)(x_h + i) = h;
    } else if (bid < 20480) {
        const int b2 = bid - 8192;                 // 12288 = 192 x 64
        const int c0 = (b2 % 192) * 32, r0 = (b2 / 192) * 32;   // C=6144, R=2048
        const int r = t >> 3, c4 = (t & 7) * 4;
        f32x4 v = *(const f32x4*)(wqkv + (long)(r0 + r) * 6144 + c0 + c4);
        f16x4 h;
#pragma unroll
        for (int e = 0; e < 4; ++e) h[e] = (_Float16)v[e];
        *(f16x4*)&tile[r][c4] = h;
        __syncthreads();
        const int oc = t >> 3, o4 = (t & 7) * 4;
        f16x4 o;
#pragma unroll
        for (int e = 0; e < 4; ++e) o[e] = tile[o4 + e][oc];
        *(f16x4*)(wqkvT + (long)(c0 + oc) * 2048 + r0 + o4) = o;
    } else {
        const int idx = (bid - 20480) * 256 + t;   // 2048*512
        const int s = idx >> 9, j = idx & 511;
        float invf = exp2f(-13.287712379549449f * (float)j * (1.0f / 512.0f));
        float ang = (float)s * invf;
        float sn, cs;
        sincosf(ang, &sn, &cs);
        cosT[idx] = cs;
        sinT[idx] = sn;
    }
}

// ---------------- RoPE in-place, 8 elems/thread (fallback path) ----------------
__global__ void rope_inplace(_Float16* __restrict__ qkv, const float* __restrict__ cosT,
                             const float* __restrict__ sinT) {
    const int t = threadIdx.x;
    const int row = blockIdx.x * 2 + (t >> 7);   // b*2048 + s
    const int s = row & 2047;
    const int j0 = (t & 127) * 8;                // [0,1024)
    _Float16* base = qkv + (long)row * 6144;
    f16x8 q0 = *(const f16x8*)(base + j0);
    f16x8 q1 = *(const f16x8*)(base + 1024 + j0);
    f16x8 k0 = *(const f16x8*)(base + 2048 + j0);
    f16x8 k1 = *(const f16x8*)(base + 3072 + j0);
    const int jj = j0 & 511;
    f32x4 cs0 = *(const f32x4*)(cosT + (long)s * 512 + jj);
    f32x4 cs1 = *(const f32x4*)(cosT + (long)s * 512 + jj + 4);
    f32x4 sn0 = *(const f32x4*)(sinT + (long)s * 512 + jj);
    f32x4 sn1 = *(const f32x4*)(sinT + (long)s * 512 + jj + 4);
    f16x8 oq0, oq1, ok0, ok1;
#pragma unroll
    for (int e = 0; e < 8; ++e) {
        const float cs = (e < 4) ? cs0[e & 3] : cs1[e & 3];
        const float sn = (e < 4) ? sn0[e & 3] : sn1[e & 3];
        float a = (float)q0[e], b = (float)q1[e];
        oq0[e] = (_Float16)(a * cs - b * sn);
        oq1[e] = (_Float16)(b * cs + a * sn);
        float c = (float)k0[e], d = (float)k1[e];
        ok0[e] = (_Float16)(c * cs - d * sn);
        ok1[e] = (_Float16)(d * cs + c * sn);
    }
    *(f16x8*)(base + j0) = oq0;
    *(f16x8*)(base + 1024 + j0) = oq1;
    *(f16x8*)(base + 2048 + j0) = ok0;
    *(f16x8*)(base + 3072 + j0) = ok1;
}

// ---------------- V transpose (fallback path) ----------------
__global__ void v_transpose(const _Float16* __restrict__ qkv, _Float16* __restrict__ vT) {
    __shared__ _Float16 tile[32][36];
    const int z = blockIdx.z, b = z >> 1, h = z & 1;
    const int s0 = blockIdx.x * 32, d0 = blockIdx.y * 32;
    const int t = threadIdx.x;
    const int r = t >> 3, c4 = (t & 7) * 4;
    const _Float16* src = qkv + (long)(b * 2048 + s0 + r) * 6144 + 4096 + h * 1024 + d0 + c4;
    *(f16x4*)&tile[r][c4] = *(const f16x4*)src;
    __syncthreads();
    const int dr = t >> 3, sc = (t & 7) * 4;
    f16x4 o;
#pragma unroll
    for (int e = 0; e < 4; ++e) o[e] = tile[sc + e][dr];
    *(f16x4*)(vT + ((long)z * 1024 + d0 + dr) * 2048 + s0 + sc) = o;
}

// ---------------- MERGED: RoPE (q,k) | V transpose (disjoint regions of qkv) ----------------
// blocks [0,4096): rope 2 rows/block; [4096,20480): v-transpose flattened (64 x 32 x 8).
__global__ __launch_bounds__(256) void rope_vt(_Float16* __restrict__ qkv,
                                               const float* __restrict__ cosT,
                                               const float* __restrict__ sinT,
                                               _Float16* __restrict__ vT) {
    __shared__ _Float16 tile[32][36];
    const int bid = blockIdx.x;
    const int t = threadIdx.x;
    if (bid < 4096) {
        const int row = bid * 2 + (t >> 7);
        const int s = row & 2047;
        const int j0 = (t & 127) * 8;
        _Float16* base = qkv + (long)row * 6144;
        f16x8 q0 = *(const f16x8*)(base + j0);
        f16x8 q1 = *(const f16x8*)(base + 1024 + j0);
        f16x8 k0 = *(const f16x8*)(base + 2048 + j0);
        f16x8 k1 = *(const f16x8*)(base + 3072 + j0);
        const int jj = j0 & 511;
        f32x4 cs0 = *(const f32x4*)(cosT + (long)s * 512 + jj);
        f32x4 cs1 = *(const f32x4*)(cosT + (long)s * 512 + jj + 4);
        f32x4 sn0 = *(const f32x4*)(sinT + (long)s * 512 + jj);
        f32x4 sn1 = *(const f32x4*)(sinT + (long)s * 512 + jj + 4);
        f16x8 oq0, oq1, ok0, ok1;
#pragma unroll
        for (int e = 0; e < 8; ++e) {
            const float cs = (e < 4) ? cs0[e & 3] : cs1[e & 3];
            const float sn = (e < 4) ? sn0[e & 3] : sn1[e & 3];
            float a = (float)q0[e], b = (float)q1[e];
            oq0[e] = (_Float16)(a * cs - b * sn);
            oq1[e] = (_Float16)(b * cs + a * sn);
            float c = (float)k0[e], d = (float)k1[e];
            ok0[e] = (_Float16)(c * cs - d * sn);
            ok1[e] = (_Float16)(d * cs + c * sn);
        }
        *(f16x8*)(base + j0) = oq0;
        *(f16x8*)(base + 1024 + j0) = oq1;
        *(f16x8*)(base + 2048 + j0) = ok0;
        *(f16x8*)(base + 3072 + j0) = ok1;
    } else {
        const int vid = bid - 4096;                // 16384 = 64 x 32 x 8
        const int z = vid >> 11, rem = vid & 2047;
        const int s0 = (rem & 63) * 32, d0 = (rem >> 6) * 32;
        const int b = z >> 1, h = z & 1;
        const int r = t >> 3, c4 = (t & 7) * 4;
        const _Float16* src = qkv + (long)(b * 2048 + s0 + r) * 6144 + 4096 + h * 1024 + d0 + c4;
        *(f16x4*)&tile[r][c4] = *(const f16x4*)src;
        __syncthreads();
        const int dr = t >> 3, sc = (t & 7) * 4;
        f16x4 o;
#pragma unroll
        for (int e = 0; e < 4; ++e) o[e] = tile[sc + e][dr];
        *(f16x4*)(vT + ((long)z * 1024 + d0 + dr) * 2048 + s0 + sc) = o;
    }
}

// ---------------- MERGED: fold 32 partials/row -> lsum | wout transpose -> woutT ----------------
// Runs after QK (pp complete; woutT's home at ws+0 is dead once QK consumed q/k).
// blocks [0,64): rowsum (16384 rows); [64,4160): wout (2048x2048) transpose, 64x64 tiles.
__global__ __launch_bounds__(256) void rowsum_wt(const float* __restrict__ p,
                                                 float* __restrict__ l,
                                                 const float* __restrict__ wout,
                                                 _Float16* __restrict__ woutT) {
    __shared__ _Float16 tile[32][36];
    const int bid = blockIdx.x;
    const int t = threadIdx.x;
    if (bid < 64) {
        const int i = bid * 256 + t;               // 16384
        const float* q = p + (long)i * 32;
        float s = 0.f;
#pragma unroll
        for (int j = 0; j < 8; ++j) {
            f32x4 a = *(const f32x4*)(q + j * 4);
            s += (a[0] + a[1]) + (a[2] + a[3]);
        }
        l[i] = s;
    } else {
        const int b2 = bid - 64;                   // 4096 = 64 x 64
        const int c0 = (b2 & 63) * 32, r0 = (b2 >> 6) * 32;   // R=C=2048
        const int r = t >> 3, c4 = (t & 7) * 4;
        f32x4 v = *(const f32x4*)(wout + (long)(r0 + r) * 2048 + c0 + c4);
        f16x4 h;
#pragma unroll
        for (int e = 0; e < 4; ++e) h[e] = (_Float16)v[e];
        *(f16x4*)&tile[r][c4] = h;
        __syncthreads();
        const int oc = t >> 3, o4 = (t & 7) * 4;
        f16x4 o;
#pragma unroll
        for (int e = 0; e < 4; ++e) o[e] = tile[o4 + e][oc];
        *(f16x4*)(woutT + (long)(c0 + oc) * 2048 + r0 + o4) = o;
    }
}

// ---------------- softmax on f32 rows (2048), writes f16 P in place (fallback path) ----------------
__global__ __launch_bounds__(256) void softmax_rows_f32(float* __restrict__ S, float scale) {
    const int wid = threadIdx.x >> 6, lane = threadIdx.x & 63;
    const long row = (long)blockIdx.x * 4 + wid;
    float* rp = S + row * 2048;
    f32x4 v[8];
    float mx = -1e30f;
#pragma unroll
    for (int i = 0; i < 8; ++i) {
        v[i] = *(const f32x4*)(rp + (i * 64 + lane) * 4);
#pragma unroll
        for (int e = 0; e < 4; ++e) mx = fmaxf(mx, v[i][e]);
    }
#pragma unroll
    for (int o = 32; o > 0; o >>= 1) mx = fmaxf(mx, __shfl_xor(mx, o, 64));
    float sum = 0.f;
#pragma unroll
    for (int i = 0; i < 8; ++i)
#pragma unroll
        for (int e = 0; e < 4; ++e) {
            float p = __expf(scale * (v[i][e] - mx));
            v[i][e] = p; sum += p;
        }
#pragma unroll
    for (int o = 32; o > 0; o >>= 1) sum += __shfl_xor(sum, o, 64);
    float inv = 1.0f / sum;
    _Float16* wp = (_Float16*)S + row * 4096;
#pragma unroll
    for (int i = 0; i < 8; ++i) {
        f16x4 h;
#pragma unroll
        for (int e = 0; e < 4; ++e) h[e] = (_Float16)(v[i][e] * inv);
        *(f16x4*)(wp + (i * 64 + lane) * 4) = h;
    }
}

// ---------------- rowsum32 (fallback path helper; unused in batched) ----------------
__global__ __launch_bounds__(256) void rowsum32(const float* __restrict__ p,
                                                float* __restrict__ l) {
    const int i = blockIdx.x * 256 + threadIdx.x;
    const float* q = p + (long)i * 32;
    float s = 0.f;
#pragma unroll
    for (int j = 0; j < 8; ++j) {
        f32x4 a = *(const f32x4*)(q + j * 4);
        s += (a[0] + a[1]) + (a[2] + a[3]);
    }
    l[i] = s;
}

// ---------------- GEMM 256x256, BK=64, 8 waves, 2-buffer LDS, 2-barrier/K-tile schedule ----------------
// BEST MEASURED STRUCTURE (rounds 15/21/22/23): per K-tile only the 2 load-bearing barriers:
//  (1) mid-tile (closes all B-fragment reads before B(g+2) overwrites current buf's B region),
//  (2) tile-end gate (counted vmcnt(4) + barrier; orders stages -> next tile's reads).
// vmcnt queue at gate: [A(g+1):4][B(g+2):4] -> vmcnt(4) retires A(g+1), leaves B(g+2).
// SWZ: 0 = natural mapping (gx%8==0 pins B-col panels per XCD; single-batch GEMMs),
//      1 = bijective chunk (m204; one z-slice per XCD; z-batched attention GEMMs).
// LDS per buffer: A 256x64 f16 [0,32K), B [32K,64K); rows 128 B; granule(16B) swizzle g^=(row&7),
// stage writes linear (global_load_lds), inverse swizzle on the GLOBAL source col.
// OMODE: 0 = f32 out (+bias), 1 = f16 out,
//        2 = f16 exp(v*scale) + DETERMINISTIC per-(block,wave) row-partials: fr-lane shfl
//            reduce, fr==0 stores aux[(z*2048+row)*32 + sbx*4 + wc] (round-21 verified),
//        3 = f16 v * rcp(aux[z*2048+row]).
template <int OMODE, bool BIAS, bool SWZ>
__global__ __launch_bounds__(512, 2)
void gemm256(const _Float16* __restrict__ A, const _Float16* __restrict__ B,
             void* __restrict__ Cv, const float* __restrict__ aux, float scale,
             int K, int lda, int ldb, int ldc, int zmod,
             long a1, long a2, long b1, long b2, long c1, long c2) {
    __shared__ char lds[131072];
    int sbx, sby, sbz;
    if (SWZ) {
        const int gx = gridDim.x, gy = gridDim.y;
        const int nwg = gx * gy * gridDim.z;
        const int orig = (blockIdx.z * gy + blockIdx.y) * gx + blockIdx.x;
        const int q8 = nwg >> 3, r8 = nwg & 7;
        const int xcd = orig & 7, sub = orig >> 3;
        const int wgid = (xcd < r8 ? xcd * (q8 + 1) : r8 * (q8 + 1) + (xcd - r8) * q8) + sub;
        sbx = wgid % gx;
        const int tmp = wgid / gx;
        sby = tmp % gy; sbz = tmp / gy;
    } else {
        sbx = blockIdx.x; sby = blockIdx.y; sbz = blockIdx.z;
    }

    const int z = sbz, zq = z / zmod, zr = z - zq * zmod;
    A += zq * a1 + zr * a2;
    B += zq * b1 + zr * b2;
    const long coff = zq * c1 + zr * c2;
    const int tm = sby * 256, tn = sbx * 256;
    const int t = threadIdx.x;
    const int lane = t & 63, wid = t >> 6;
    const int wr = wid >> 2, wc = wid & 3;     // wave tile: rows wr*128, cols wc*64
    const int fr = lane & 15, kg = lane >> 4;

    // staging source (inverse-swizzled global col)
    const int strow = wid * 16 + (lane >> 3);
    const int stcol = ((lane & 7) ^ (lane >> 3)) * 8;
    const _Float16* gA = A + (long)(tm + strow) * lda + stcol;
    const _Float16* gB = B + (long)(tn + strow) * ldb + stcol;
    char* const ldsw = lds + wid * 2048;       // wave's linear chunk base (+1024 for 2nd load)

    // ds_read swizzled granule offsets (per lane, k-half h in {0,1})
    const int sw0 = 16 * ((0 * 4 + kg) ^ (fr & 7));
    const int sw1 = 16 * ((1 * 4 + kg) ^ (fr & 7));

    const int NT = K >> 6;
    f32x4 acc[8][4] = {};

    auto stageA = [&](int tt, int h) {
        const _Float16* s = gA + (long)(h * 128) * lda + tt * 64;
        char* d = ldsw + (tt & 1) * 65536 + h * 16384;
        gload_lds16(s, d);
        gload_lds16(s + (long)8 * lda, d + 1024);
    };
    auto stageB = [&](int tt, int h) {
        const _Float16* s = gB + (long)(h * 128) * ldb + tt * 64;
        char* d = ldsw + (tt & 1) * 65536 + 32768 + h * 16384;
        gload_lds16(s, d);
        gload_lds16(s + (long)8 * ldb, d + 1024);
    };

    // prologue: B(0), A(0) -> buf0; B(1) -> buf1; gate tile0 (vmcnt(4) leaves B(1) in flight)
    stageB(0, 0); stageB(0, 1); stageA(0, 0); stageA(0, 1);
    stageB(1, 0); stageB(1, 1);
    asm volatile("s_waitcnt vmcnt(4)" ::: "memory");
    barrier_fenced();

    f16x8 bf0[2][2], bf1[2][2];
    const int arow = (wr * 128 + fr) * 128;          // byte row base for A frags
    const int brow = 32768 + (wc * 64 + fr) * 128;   // byte row base for B frags

    for (int g = 0; g < NT; ++g) {
        const char* buf = lds + (g & 1) * 65536;
        // ---- half A: quadrants Q(0,0) + Q(0,1); stage A(g+1) into buf^1
        f16x8 af0[4][2];
#pragma unroll
        for (int m = 0; m < 4; ++m) {
            af0[m][0] = *(const f16x8*)(buf + arow + m * 2048 + sw0);
            af0[m][1] = *(const f16x8*)(buf + arow + m * 2048 + sw1);
        }
#pragma unroll
        for (int n = 0; n < 2; ++n) {
            bf0[n][0] = *(const f16x8*)(buf + brow + n * 2048 + sw0);
            bf0[n][1] = *(const f16x8*)(buf + brow + n * 2048 + sw1);
            bf1[n][0] = *(const f16x8*)(buf + brow + 4096 + n * 2048 + sw0);
            bf1[n][1] = *(const f16x8*)(buf + brow + 4096 + n * 2048 + sw1);
        }
        if (g + 1 < NT) { stageA(g + 1, 0); stageA(g + 1, 1); }
        __builtin_amdgcn_s_setprio(1);
#pragma unroll
        for (int m = 0; m < 4; ++m)
#pragma unroll
            for (int n = 0; n < 2; ++n)
#pragma unroll
                for (int k = 0; k < 2; ++k) {
                    acc[m][n]     = __builtin_amdgcn_mfma_f32_16x16x32_f16(af0[m][k], bf0[n][k], acc[m][n], 0, 0, 0);
                    acc[m][n + 2] = __builtin_amdgcn_mfma_f32_16x16x32_f16(af0[m][k], bf1[n][k], acc[m][n + 2], 0, 0, 0);
                }
        __builtin_amdgcn_s_setprio(0);
        barrier_fenced();   // closes all B reads: B(g+2) may now overwrite current B region
        // ---- half B: quadrants Q(1,1) + Q(1,0); stage B(g+2) into current buf
        f16x8 af1[4][2];
#pragma unroll
        for (int m = 0; m < 4; ++m) {
            af1[m][0] = *(const f16x8*)(buf + arow + 8192 + m * 2048 + sw0);
            af1[m][1] = *(const f16x8*)(buf + arow + 8192 + m * 2048 + sw1);
        }
        if (g + 2 < NT) { stageB(g + 2, 0); stageB(g + 2, 1); }
        __builtin_amdgcn_s_setprio(1);
#pragma unroll
        for (int m = 0; m < 4; ++m)
#pragma unroll
            for (int n = 0; n < 2; ++n)
#pragma unroll
                for (int k = 0; k < 2; ++k) {
                    acc[m + 4][n + 2] = __builtin_amdgcn_mfma_f32_16x16x32_f16(af1[m][k], bf1[n][k], acc[m + 4][n + 2], 0, 0, 0);
                    acc[m + 4][n]     = __builtin_amdgcn_mfma_f32_16x16x32_f16(af1[m][k], bf0[n][k], acc[m + 4][n], 0, 0, 0);
                }
        __builtin_amdgcn_s_setprio(0);
        // ---- gate for tile g+1 (counted; never drains mid-loop)
        if (g + 2 < NT)      asm volatile("s_waitcnt vmcnt(4)" ::: "memory");
        else if (g + 1 < NT) asm volatile("s_waitcnt vmcnt(0)" ::: "memory");
        barrier_fenced();   // also closes A(mg=1) reads before next tile's A(g+2) stage
    }

    // epilogue: C/D layout col = lane&15, row = (lane>>4)*4 + r
    const int rb = tm + wr * 128 + (lane >> 4) * 4;
    const int cb = tn + wc * 64 + fr;
    const float* auxz = (OMODE == 3) ? (aux + (long)z * 2048) : aux;
#pragma unroll
    for (int m = 0; m < 8; ++m) {
#pragma unroll
        for (int r = 0; r < 4; ++r) {
            const int row = rb + m * 16 + r;
            float inv = 1.0f;
            if (OMODE == 3) inv = __builtin_amdgcn_rcpf(auxz[row]);
            float rsum = 0.f;
#pragma unroll
            for (int n = 0; n < 4; ++n) {
                float v = acc[m][n][r];
                const int col = cb + n * 16;
                if (BIAS) v += aux[col];
                if (OMODE == 0) {
                    ((float*)Cv)[coff + (long)row * ldc + col] = v;
                } else {
                    if (OMODE == 2) { v = __expf(v * scale); rsum += v; }
                    if (OMODE == 3) v *= inv;
                    ((_Float16*)Cv)[coff + (long)row * ldc + col] = (_Float16)v;
                }
            }
            if (OMODE == 2) {
#pragma unroll
                for (int o = 1; o < 16; o <<= 1) rsum += __shfl_xor(rsum, o, 64);
                if (fr == 0)
                    ((float*)aux)[(((long)z * 2048 + row) << 5) + sbx * 4 + wc] = rsum;
            }
        }
    }
}

extern "C" void kernel_launch(void* const* d_in, const int* in_sizes, int n_in,
                              void* d_out, int out_size, void* d_ws, size_t ws_size,
                              hipStream_t stream) {
    const float* x    = (const float*)d_in[0];   // (4,2048,2048)
    const float* wqkv = (const float*)d_in[1];   // (2048,6144)
    const float* wout = (const float*)d_in[2];   // (2048,2048)
    const float* bout = (const float*)d_in[3];   // (2048,)
    char* ws = (char*)d_ws;

    _Float16* qkv_h = (_Float16*)(ws);
    _Float16* x_h   = (_Float16*)(ws + 100663296);
    _Float16* wqkvT = (_Float16*)(ws + 134217728);
    _Float16* vT    = (_Float16*)(ws + 100663296);
    _Float16* woutT = (_Float16*)(ws);
    const bool batched = ws_size >= 234946560ULL;  // incl. 64KB lsum buffer

    if (batched) {
        // tables live in the gap after wqkvT, inside the future-S16 region; they are
        // consumed by rope_vt BEFORE QK overwrites the region with S16.
        float*    cosT = (float*)(ws + 159383552);
        float*    sinT = (float*)(ws + 163577856);
        _Float16* S16  = (_Float16*)(ws + 134217728);
        float*    pp   = (float*)(ws + 201326592);   // 16384x32 f32 partials (2MB; aliases aout,
                                                     // fully consumed by rowsum_wt before PV)
        _Float16* aout = (_Float16*)(ws + 201326592);
        float*    lsum = (float*)(ws + 234881024);   // 16384 f32
        // 1. merged pre-pass: x->f16 | wqkvT | RoPE tables
        pre_pass<<<dim3(24576), dim3(256), 0, stream>>>(x, x_h, wqkv, wqkvT, cosT, sinT);
        // 2. qkv = x @ wqkv  [natural order: XCD = bx%8 pins B cols]
        gemm256<1, false, false><<<dim3(24, 32, 1), dim3(512), 0, stream>>>(
            x_h, wqkvT, (void*)qkv_h, nullptr, 0.f, 2048, 2048, 2048, 6144,
            1, 0L, 0L, 0L, 0L, 0L, 0L);
        // 3. merged RoPE (q,k in place) | V transpose -> vT
        rope_vt<<<dim3(20480), dim3(256), 0, stream>>>(qkv_h, cosT, sinT, vT);
        // 4. S~ = exp(scale * Q@K^T) + per-(block,wave) row partials  [SWZ: z-slice per XCD]
        gemm256<2, false, true><<<dim3(8, 8, 8), dim3(512), 0, stream>>>(
            qkv_h, qkv_h + 2048, (void*)S16, pp, 0.03125f, 1024, 6144, 6144, 2048,
            2, 12582912L, 1024L, 12582912L, 1024L, 8388608L, 4194304L);
        // 5. merged: fold partials -> lsum | wout transpose -> woutT (ws+0 dead after QK)
        rowsum_wt<<<dim3(4160), dim3(256), 0, stream>>>(pp, lsum, wout, woutT);
        // 6. O = (S~ @ V) / l  [SWZ; aout overwrites consumed pp]
        gemm256<3, false, true><<<dim3(4, 8, 8), dim3(512), 0, stream>>>(
            S16, vT, (void*)aout, lsum, 0.f, 2048, 2048, 2048, 2048,
            2, 8388608L, 4194304L, 4194304L, 2097152L, 4194304L, 1024L);
        // 7. out = aout @ wout + bout  [natural order]
        gemm256<0, true, false><<<dim3(8, 32, 1), dim3(512), 0, stream>>>(
            aout, woutT, d_out, bout, 0.f, 2048, 2048, 2048, 2048,
            1, 0L, 0L, 0L, 0L, 0L, 0L);
    } else {
        float*    cosT = (float*)(ws + 100663296);
        float*    sinT = (float*)(ws + 104857600);
        float*    S32  = (float*)(ws + 134217728);
        _Float16* aout = (_Float16*)(ws + 150994944);
        f32_to_f16_vec<<<dim3(8192), dim3(256), 0, stream>>>(x, x_h);
        transpose_f32_to_f16<<<dim3(192, 64), dim3(256), 0, stream>>>(wqkv, wqkvT, 2048, 6144);
        gemm256<1, false, false><<<dim3(24, 32, 1), dim3(512), 0, stream>>>(
            x_h, wqkvT, (void*)qkv_h, nullptr, 0.f, 2048, 2048, 2048, 6144,
            1, 0L, 0L, 0L, 0L, 0L, 0L);
        rope_tables_k<<<dim3(4096), dim3(256), 0, stream>>>(cosT, sinT);
        rope_inplace<<<dim3(4096), dim3(256), 0, stream>>>(qkv_h, cosT, sinT);
        v_transpose<<<dim3(64, 32, 8), dim3(256), 0, stream>>>(qkv_h, vT);
        for (int z = 0; z < 8; ++z) {
            const _Float16* Az = qkv_h + (long)(z >> 1) * 12582912 + (z & 1) * 1024;
            gemm256<0, false, false><<<dim3(8, 8, 1), dim3(512), 0, stream>>>(
                Az, Az + 2048, (void*)S32, nullptr, 0.f, 1024, 6144, 6144, 2048,
                1, 0L, 0L, 0L, 0L, 0L, 0L);
            softmax_rows_f32<<<dim3(512), dim3(256), 0, stream>>>(S32, 0.03125f);
            gemm256<1, false, false><<<dim3(4, 8, 1), dim3(512), 0, stream>>>(
                (const _Float16*)S32, vT + (long)z * 2097152,
                (void*)(aout + (long)(z >> 1) * 4194304 + (z & 1) * 1024), nullptr, 0.f,
                2048, 4096, 2048, 2048, 1, 0L, 0L, 0L, 0L, 0L, 0L);
        }
        transpose_f32_to_f16<<<dim3(64, 64), dim3(256), 0, stream>>>(wout, woutT, 2048, 2048);
        gemm256<0, true, false><<<dim3(8, 32, 1), dim3(512), 0, stream>>>(
            aout, woutT, d_out, bout, 0.f, 2048, 2048, 2048, 2048,
            1, 0L, 0L, 0L, 0L, 0L, 0L);
    }
}